// Round 2
// baseline (815.989 us; speedup 1.0000x reference)
//
#include <hip/hip_runtime.h>
#include <hip/hip_bf16.h>
#include <math.h>

#define NN 100000
#define EE 1600000
#define ET 1700000   // E + N self-loops
#define HID 32

// ---- init: a0 = x0 ----
__global__ __launch_bounds__(256) void k_init(const float* __restrict__ x0, float* __restrict__ a0) {
    int t = blockIdx.x * 256 + threadIdx.x;
    if (t < NN) a0[t] = x0[t];
}

// ---- layer-1 aggregation (1 feature) ----
__global__ __launch_bounds__(256) void k_scatter1(const int* __restrict__ src32, const int* __restrict__ dst32,
                                                  const float* __restrict__ x0, float* __restrict__ a0) {
    int t = blockIdx.x * 256 + threadIdx.x;
    if (t < ET) atomicAdd(&a0[dst32[t]], x0[src32[t]]);
}

// ---- layer-1 linear (1 -> 32) + relu ----
__global__ __launch_bounds__(256) void k_layer1(const float* __restrict__ a0, const float* __restrict__ W1,
                                                const float* __restrict__ b1, float* __restrict__ h) {
    int t = blockIdx.x * 256 + threadIdx.x;  // t < NN*32
    int i = t >> 5, j = t & 31;
    float v = fmaf(a0[i], W1[j], b1[j]);
    h[t] = fmaxf(v, 0.f);
}

// ---- agg init: agg = h (the "+x" term; self-loops in the edge list give the rest) ----
__global__ __launch_bounds__(256) void k_copy(const float* __restrict__ s, float* __restrict__ d) {
    int t = blockIdx.x * 256 + threadIdx.x;  // t < NN*32/4
    reinterpret_cast<float4*>(d)[t] = reinterpret_cast<const float4*>(s)[t];
}

// ---- 32-feature scatter-add over all edges (incl. self-loops) ----
__global__ __launch_bounds__(256) void k_scatter32(const int* __restrict__ src32, const int* __restrict__ dst32,
                                                   const float* __restrict__ h, float* __restrict__ agg) {
    int t = blockIdx.x * 256 + threadIdx.x;  // t < ET*32
    int e = t >> 5;
    int j = t & 31;
    int s = src32[e], d = dst32[e];
    atomicAdd(&agg[d * 32 + j], h[s * 32 + j]);
}

// ---- 32x32 node linear, in-place (wave-safe: row fully owned by one 32-lane group) ----
template <int RELU>
__global__ __launch_bounds__(256) void k_matmul(float* __restrict__ agg, const float* __restrict__ W,
                                                const float* __restrict__ b) {
    int t = blockIdx.x * 256 + threadIdx.x;  // t < NN*32
    int j = t & 31;
    float v = agg[t];
    float acc = b[j];
#pragma unroll
    for (int k = 0; k < 32; ++k) {
        float xk = __shfl(v, k, 32);
        acc = fmaf(xk, W[k * 32 + j], acc);
    }
    if (RELU) acc = fmaxf(acc, 0.f);
    agg[t] = acc;
}

// ---- per-edge MLP (concat 64 -> 32 prelu -> 2) + persistence-image partial sums ----
__global__ __launch_bounds__(256) void k_edge(const int* __restrict__ src32, const int* __restrict__ dst32,
                                              const float* __restrict__ x4,
                                              const float* __restrict__ W5, const float* __restrict__ b5,
                                              const float* __restrict__ W6, const float* __restrict__ b6,
                                              float* __restrict__ pd_out, float* __restrict__ partial) {
    int e = blockIdx.x * 256 + threadIdx.x;  // EE divisible by 256, no tail
    int s = src32[e], d = dst32[e];

    float acc[32];
#pragma unroll
    for (int j = 0; j < 32; ++j) acc[j] = b5[j];

    float xv[32];
    {
        const float4* p = reinterpret_cast<const float4*>(x4 + (size_t)s * 32);
#pragma unroll
        for (int u = 0; u < 8; ++u) {
            float4 q = p[u];
            xv[4 * u + 0] = q.x; xv[4 * u + 1] = q.y; xv[4 * u + 2] = q.z; xv[4 * u + 3] = q.w;
        }
    }
#pragma unroll 8
    for (int k = 0; k < 32; ++k) {
        float xk = xv[k];
#pragma unroll
        for (int j = 0; j < 32; ++j) acc[j] = fmaf(xk, W5[k * 32 + j], acc[j]);
    }
    {
        const float4* p = reinterpret_cast<const float4*>(x4 + (size_t)d * 32);
#pragma unroll
        for (int u = 0; u < 8; ++u) {
            float4 q = p[u];
            xv[4 * u + 0] = q.x; xv[4 * u + 1] = q.y; xv[4 * u + 2] = q.z; xv[4 * u + 3] = q.w;
        }
    }
#pragma unroll 8
    for (int k = 0; k < 32; ++k) {
        float xk = xv[k];
#pragma unroll
        for (int j = 0; j < 32; ++j) acc[j] = fmaf(xk, W5[(32 + k) * 32 + j], acc[j]);
    }

    float pd0 = b6[0], pd1 = b6[1];
#pragma unroll
    for (int j = 0; j < 32; ++j) {
        float hj = acc[j];
        hj = hj >= 0.f ? hj : 0.1f * hj;  // prelu
        pd0 = fmaf(hj, W6[2 * j + 0], pd0);
        pd1 = fmaf(hj, W6[2 * j + 1], pd1);
    }
    pd_out[2 * (size_t)e + 0] = pd0;
    pd_out[2 * (size_t)e + 1] = pd1;

    // persistence image contribution
    float pers = pd1 - pd0;
    const float inv = 3.5355339059327378f;  // 1/(0.2*sqrt(2))
    float cb[6], cp[6];
#pragma unroll
    for (int i = 0; i < 6; ++i) {
        float te = 0.2f * (float)i;
        cb[i] = 0.5f * (1.f + erff((te - pd0) * inv));
        cp[i] = 0.5f * (1.f + erff((te - pers) * inv));
    }

    int lane = threadIdx.x & 63;
    int wv = threadIdx.x >> 6;
    __shared__ float sacc[4][25];
#pragma unroll
    for (int i = 0; i < 5; ++i) {
#pragma unroll
        for (int jj = 0; jj < 5; ++jj) {
            float v = pers * (cb[i + 1] - cb[i]) * (cp[jj + 1] - cp[jj]);
            v += __shfl_down(v, 32);
            v += __shfl_down(v, 16);
            v += __shfl_down(v, 8);
            v += __shfl_down(v, 4);
            v += __shfl_down(v, 2);
            v += __shfl_down(v, 1);
            if (lane == 0) sacc[wv][i * 5 + jj] = v;
        }
    }
    __syncthreads();
    if (threadIdx.x < 25) {
        partial[(size_t)blockIdx.x * 25 + threadIdx.x] =
            sacc[0][threadIdx.x] + sacc[1][threadIdx.x] + sacc[2][threadIdx.x] + sacc[3][threadIdx.x];
    }
}

// ---- deterministic final reduction of 6250 block partials per bin ----
__global__ __launch_bounds__(256) void k_img(const float* __restrict__ partial, float* __restrict__ img) {
    int bin = blockIdx.x;  // 25 blocks
    float s = 0.f;
    for (int k = threadIdx.x; k < EE / 256; k += 256) s += partial[(size_t)k * 25 + bin];
    s += __shfl_down(s, 32);
    s += __shfl_down(s, 16);
    s += __shfl_down(s, 8);
    s += __shfl_down(s, 4);
    s += __shfl_down(s, 2);
    s += __shfl_down(s, 1);
    __shared__ float wsum[4];
    if ((threadIdx.x & 63) == 0) wsum[threadIdx.x >> 6] = s;
    __syncthreads();
    if (threadIdx.x == 0) img[bin] = wsum[0] + wsum[1] + wsum[2] + wsum[3];
}

extern "C" void kernel_launch(void* const* d_in, const int* in_sizes, int n_in,
                              void* d_out, int out_size, void* d_ws, size_t ws_size,
                              hipStream_t stream) {
    const float* x0 = (const float*)d_in[0];
    // Harness converts integer inputs to int32: edge_index0 is (2, ET) int32.
    const int* src32 = (const int*)d_in[1];
    const int* dst32 = src32 + ET;
    const float* W1 = (const float*)d_in[2];
    const float* b1 = (const float*)d_in[3];
    const float* W2 = (const float*)d_in[4];
    const float* b2 = (const float*)d_in[5];
    const float* W4 = (const float*)d_in[6];
    const float* b4 = (const float*)d_in[7];
    const float* W3 = (const float*)d_in[8];
    const float* b3 = (const float*)d_in[9];
    const float* W5 = (const float*)d_in[10];
    const float* b5 = (const float*)d_in[11];
    const float* W6 = (const float*)d_in[12];
    const float* b6 = (const float*)d_in[13];
    float* out = (float*)d_out;

    char* w = (char*)d_ws;
    float* bufA = (float*)w;                       // NN*32 floats
    float* bufB = bufA + (size_t)NN * 32;          // NN*32 floats
    float* a0 = bufB + (size_t)NN * 32;            // NN floats
    float* partial = a0 + NN;                      // (EE/256)*25 floats

    k_init<<<(NN + 255) / 256, 256, 0, stream>>>(x0, a0);
    k_scatter1<<<(ET + 255) / 256, 256, 0, stream>>>(src32, dst32, x0, a0);
    k_layer1<<<NN * 32 / 256, 256, 0, stream>>>(a0, W1, b1, bufA);

    // layer 2: agg into bufB from bufA, W2+relu
    k_copy<<<NN * 32 / 4 / 256, 256, 0, stream>>>(bufA, bufB);
    k_scatter32<<<ET * 32 / 256, 256, 0, stream>>>(src32, dst32, bufA, bufB);
    k_matmul<1><<<NN * 32 / 256, 256, 0, stream>>>(bufB, W2, b2);

    // layer 3: agg into bufA from bufB, W4+relu
    k_copy<<<NN * 32 / 4 / 256, 256, 0, stream>>>(bufB, bufA);
    k_scatter32<<<ET * 32 / 256, 256, 0, stream>>>(src32, dst32, bufB, bufA);
    k_matmul<1><<<NN * 32 / 256, 256, 0, stream>>>(bufA, W4, b4);

    // layer 4: agg into bufB from bufA, W3, no relu
    k_copy<<<NN * 32 / 4 / 256, 256, 0, stream>>>(bufA, bufB);
    k_scatter32<<<ET * 32 / 256, 256, 0, stream>>>(src32, dst32, bufA, bufB);
    k_matmul<0><<<NN * 32 / 256, 256, 0, stream>>>(bufB, W3, b3);

    // edge MLP + persistence image
    k_edge<<<EE / 256, 256, 0, stream>>>(src32, dst32, bufB, W5, b5, W6, b6, out, partial);
    k_img<<<25, 256, 0, stream>>>(partial, out + 2 * (size_t)EE);
}

// Round 3
// 803.211 us; speedup vs baseline: 1.0159x; 1.0159x over previous
//
#include <hip/hip_runtime.h>
#include <hip/hip_bf16.h>
#include <math.h>

#define NN 100000
#define EE 1600000
#define ET 1700000   // E + N self-loops
#define HID 32

// ---- zero int buffer ----
__global__ __launch_bounds__(256) void k_zero(int* __restrict__ p, int n) {
    int t = blockIdx.x * 256 + threadIdx.x;
    if (t < n) p[t] = 0;
}

// ---- degree histogram over dst ----
__global__ __launch_bounds__(256) void k_hist(const int* __restrict__ dst32, int* __restrict__ deg) {
    int t = blockIdx.x * 256 + threadIdx.x;
    if (t < ET) atomicAdd(&deg[dst32[t]], 1);
}

// ---- single-block exclusive scan of deg -> rowptr (NN+1) ----
__global__ __launch_bounds__(1024) void k_scan(const int* __restrict__ deg, int* __restrict__ rowptr) {
    __shared__ int s[1024];
    int t = threadIdx.x;
    const int chunk = (NN + 1023) / 1024;  // 98
    int lo = t * chunk, hi = lo + chunk;
    if (hi > NN) hi = NN;
    int sum = 0;
    for (int i = lo; i < hi; ++i) sum += deg[i];
    s[t] = sum;
    for (int off = 1; off < 1024; off <<= 1) {
        __syncthreads();
        int v = (t >= off) ? s[t - off] : 0;
        __syncthreads();
        s[t] += v;
    }
    __syncthreads();
    int run = (t == 0) ? 0 : s[t - 1];
    for (int i = lo; i < hi; ++i) {
        rowptr[i] = run;
        run += deg[i];
    }
    if (t == 0) rowptr[NN] = ET;
}

// ---- pos = rowptr[0..NN) ----
__global__ __launch_bounds__(256) void k_pos(const int* __restrict__ rowptr, int* __restrict__ pos) {
    int t = blockIdx.x * 256 + threadIdx.x;
    if (t < NN) pos[t] = rowptr[t];
}

// ---- bucket-fill src indices by dst ----
__global__ __launch_bounds__(256) void k_fill(const int* __restrict__ src32, const int* __restrict__ dst32,
                                              int* __restrict__ pos, int* __restrict__ src_sorted) {
    int t = blockIdx.x * 256 + threadIdx.x;
    if (t < ET) {
        int d = dst32[t];
        int slot = atomicAdd(&pos[d], 1);
        src_sorted[slot] = src32[t];
    }
}

// ---- layer 1: pull-agg (1 feat) + linear 1->32 + relu, group-per-node ----
__global__ __launch_bounds__(256) void k_pull1(const int* __restrict__ rowptr, const int* __restrict__ src_sorted,
                                               const float* __restrict__ x0, const float* __restrict__ W1,
                                               const float* __restrict__ b1, float* __restrict__ hout) {
    int g = (blockIdx.x * 256 + threadIdx.x) >> 5;
    if (g >= NN) return;
    int j = threadIdx.x & 31;
    float s = x0[g];
    int e1 = rowptr[g + 1];
    for (int e = rowptr[g]; e < e1; ++e) s += x0[src_sorted[e]];
    hout[(size_t)g * 32 + j] = fmaxf(fmaf(s, W1[j], b1[j]), 0.f);
}

// ---- fused pull-agg (32 feat) + 32x32 matmul (+relu), group-per-node ----
template <int RELU>
__global__ __launch_bounds__(256) void k_agg_mm(const int* __restrict__ rowptr, const int* __restrict__ src_sorted,
                                                const float* __restrict__ hin, const float* __restrict__ W,
                                                const float* __restrict__ b, float* __restrict__ hout) {
    int g = (blockIdx.x * 256 + threadIdx.x) >> 5;
    if (g >= NN) return;
    int j = threadIdx.x & 31;
    float acc = hin[(size_t)g * 32 + j];
    int e0 = rowptr[g], e1 = rowptr[g + 1];
    for (int e = e0; e < e1; ++e) {
        int s = src_sorted[e];
        acc += hin[(size_t)s * 32 + j];
    }
    float o = b[j];
#pragma unroll
    for (int k = 0; k < 32; ++k) o = fmaf(__shfl(acc, k, 32), W[k * 32 + j], o);
    if (RELU) o = fmaxf(o, 0.f);
    hout[(size_t)g * 32 + j] = o;
}

// ---- per-edge MLP (concat 64 -> 32 prelu -> 2) + persistence-image partial sums ----
__global__ __launch_bounds__(256) void k_edge(const int* __restrict__ src32, const int* __restrict__ dst32,
                                              const float* __restrict__ x4,
                                              const float* __restrict__ W5, const float* __restrict__ b5,
                                              const float* __restrict__ W6, const float* __restrict__ b6,
                                              float* __restrict__ pd_out, float* __restrict__ partial) {
    int e = blockIdx.x * 256 + threadIdx.x;  // EE divisible by 256, no tail
    int s = src32[e], d = dst32[e];

    float acc[32];
#pragma unroll
    for (int j = 0; j < 32; ++j) acc[j] = b5[j];

    float xv[32];
    {
        const float4* p = reinterpret_cast<const float4*>(x4 + (size_t)s * 32);
#pragma unroll
        for (int u = 0; u < 8; ++u) {
            float4 q = p[u];
            xv[4 * u + 0] = q.x; xv[4 * u + 1] = q.y; xv[4 * u + 2] = q.z; xv[4 * u + 3] = q.w;
        }
    }
#pragma unroll 8
    for (int k = 0; k < 32; ++k) {
        float xk = xv[k];
#pragma unroll
        for (int j = 0; j < 32; ++j) acc[j] = fmaf(xk, W5[k * 32 + j], acc[j]);
    }
    {
        const float4* p = reinterpret_cast<const float4*>(x4 + (size_t)d * 32);
#pragma unroll
        for (int u = 0; u < 8; ++u) {
            float4 q = p[u];
            xv[4 * u + 0] = q.x; xv[4 * u + 1] = q.y; xv[4 * u + 2] = q.z; xv[4 * u + 3] = q.w;
        }
    }
#pragma unroll 8
    for (int k = 0; k < 32; ++k) {
        float xk = xv[k];
#pragma unroll
        for (int j = 0; j < 32; ++j) acc[j] = fmaf(xk, W5[(32 + k) * 32 + j], acc[j]);
    }

    float pd0 = b6[0], pd1 = b6[1];
#pragma unroll
    for (int j = 0; j < 32; ++j) {
        float hj = acc[j];
        hj = hj >= 0.f ? hj : 0.1f * hj;  // prelu
        pd0 = fmaf(hj, W6[2 * j + 0], pd0);
        pd1 = fmaf(hj, W6[2 * j + 1], pd1);
    }
    pd_out[2 * (size_t)e + 0] = pd0;
    pd_out[2 * (size_t)e + 1] = pd1;

    // persistence image contribution
    float pers = pd1 - pd0;
    const float inv = 3.5355339059327378f;  // 1/(0.2*sqrt(2))
    float cb[6], cp[6];
#pragma unroll
    for (int i = 0; i < 6; ++i) {
        float te = 0.2f * (float)i;
        cb[i] = 0.5f * (1.f + erff((te - pd0) * inv));
        cp[i] = 0.5f * (1.f + erff((te - pers) * inv));
    }

    int lane = threadIdx.x & 63;
    int wv = threadIdx.x >> 6;
    __shared__ float sacc[4][25];
#pragma unroll
    for (int i = 0; i < 5; ++i) {
#pragma unroll
        for (int jj = 0; jj < 5; ++jj) {
            float v = pers * (cb[i + 1] - cb[i]) * (cp[jj + 1] - cp[jj]);
            v += __shfl_down(v, 32);
            v += __shfl_down(v, 16);
            v += __shfl_down(v, 8);
            v += __shfl_down(v, 4);
            v += __shfl_down(v, 2);
            v += __shfl_down(v, 1);
            if (lane == 0) sacc[wv][i * 5 + jj] = v;
        }
    }
    __syncthreads();
    if (threadIdx.x < 25) {
        partial[(size_t)blockIdx.x * 25 + threadIdx.x] =
            sacc[0][threadIdx.x] + sacc[1][threadIdx.x] + sacc[2][threadIdx.x] + sacc[3][threadIdx.x];
    }
}

// ---- deterministic final reduction of block partials per bin ----
__global__ __launch_bounds__(256) void k_img(const float* __restrict__ partial, float* __restrict__ img) {
    int bin = blockIdx.x;  // 25 blocks
    float s = 0.f;
    for (int k = threadIdx.x; k < EE / 256; k += 256) s += partial[(size_t)k * 25 + bin];
    s += __shfl_down(s, 32);
    s += __shfl_down(s, 16);
    s += __shfl_down(s, 8);
    s += __shfl_down(s, 4);
    s += __shfl_down(s, 2);
    s += __shfl_down(s, 1);
    __shared__ float wsum[4];
    if ((threadIdx.x & 63) == 0) wsum[threadIdx.x >> 6] = s;
    __syncthreads();
    if (threadIdx.x == 0) img[bin] = wsum[0] + wsum[1] + wsum[2] + wsum[3];
}

extern "C" void kernel_launch(void* const* d_in, const int* in_sizes, int n_in,
                              void* d_out, int out_size, void* d_ws, size_t ws_size,
                              hipStream_t stream) {
    const float* x0 = (const float*)d_in[0];
    // Harness converts integer inputs to int32: edge_index0 is (2, ET) int32.
    const int* src32 = (const int*)d_in[1];
    const int* dst32 = src32 + ET;
    const float* W1 = (const float*)d_in[2];
    const float* b1 = (const float*)d_in[3];
    const float* W2 = (const float*)d_in[4];
    const float* b2 = (const float*)d_in[5];
    const float* W4 = (const float*)d_in[6];
    const float* b4 = (const float*)d_in[7];
    const float* W3 = (const float*)d_in[8];
    const float* b3 = (const float*)d_in[9];
    const float* W5 = (const float*)d_in[10];
    const float* b5 = (const float*)d_in[11];
    const float* W6 = (const float*)d_in[12];
    const float* b6 = (const float*)d_in[13];
    float* out = (float*)d_out;

    char* w = (char*)d_ws;
    int* deg = (int*)w;                             // NN
    int* rowptr = deg + NN;                         // NN+1
    int* pos = rowptr + NN + 1;                     // NN
    int* src_sorted = pos + NN;                     // ET
    float* bufA = (float*)(src_sorted + ET);        // NN*32
    float* bufB = bufA + (size_t)NN * 32;           // NN*32
    float* partial = bufB + (size_t)NN * 32;        // (EE/256)*25

    // ---- build CSR (dst-bucketed) ----
    k_zero<<<(NN + 255) / 256, 256, 0, stream>>>(deg, NN);
    k_hist<<<(ET + 255) / 256, 256, 0, stream>>>(dst32, deg);
    k_scan<<<1, 1024, 0, stream>>>(deg, rowptr);
    k_pos<<<(NN + 255) / 256, 256, 0, stream>>>(rowptr, pos);
    k_fill<<<(ET + 255) / 256, 256, 0, stream>>>(src32, dst32, pos, src_sorted);

    // ---- layer 1 (pull + 1->32 + relu) ----
    k_pull1<<<(NN * 32 + 255) / 256, 256, 0, stream>>>(rowptr, src_sorted, x0, W1, b1, bufA);
    // ---- layers 2-4: fused pull-agg + matmul ----
    k_agg_mm<1><<<(NN * 32 + 255) / 256, 256, 0, stream>>>(rowptr, src_sorted, bufA, W2, b2, bufB);
    k_agg_mm<1><<<(NN * 32 + 255) / 256, 256, 0, stream>>>(rowptr, src_sorted, bufB, W4, b4, bufA);
    k_agg_mm<0><<<(NN * 32 + 255) / 256, 256, 0, stream>>>(rowptr, src_sorted, bufA, W3, b3, bufB);

    // ---- edge MLP + persistence image ----
    k_edge<<<EE / 256, 256, 0, stream>>>(src32, dst32, bufB, W5, b5, W6, b6, out, partial);
    k_img<<<25, 256, 0, stream>>>(partial, out + 2 * (size_t)EE);
}

// Round 4
// 504.728 us; speedup vs baseline: 1.6167x; 1.5914x over previous
//
#include <hip/hip_runtime.h>
#include <hip/hip_bf16.h>
#include <math.h>

#define NN 100000
#define EE 1600000
#define ET 1700000   // E + N self-loops
#define HID 32
#define NB ((NN + 255) / 256)   // 391 blocks for per-block scan

// ---- zero int buffer ----
__global__ __launch_bounds__(256) void k_zero(int* __restrict__ p, int n) {
    int t = blockIdx.x * 256 + threadIdx.x;
    if (t < n) p[t] = 0;
}

// ---- degree histogram over dst ----
__global__ __launch_bounds__(256) void k_hist(const int* __restrict__ dst32, int* __restrict__ deg) {
    int t = blockIdx.x * 256 + threadIdx.x;
    if (t < ET) atomicAdd(&deg[dst32[t]], 1);
}

// ---- scan stage 1: per-block sums of deg ----
__global__ __launch_bounds__(256) void k_blocksum(const int* __restrict__ deg, int* __restrict__ bsum) {
    int i = blockIdx.x * 256 + threadIdx.x;
    int v = (i < NN) ? deg[i] : 0;
    v += __shfl_down(v, 32);
    v += __shfl_down(v, 16);
    v += __shfl_down(v, 8);
    v += __shfl_down(v, 4);
    v += __shfl_down(v, 2);
    v += __shfl_down(v, 1);
    __shared__ int ws[4];
    if ((threadIdx.x & 63) == 0) ws[threadIdx.x >> 6] = v;
    __syncthreads();
    if (threadIdx.x == 0) bsum[blockIdx.x] = ws[0] + ws[1] + ws[2] + ws[3];
}

// ---- scan stage 2: exclusive scan of NB block sums (single block, 512 thr) ----
__global__ __launch_bounds__(512) void k_scanb(const int* __restrict__ bsum, int* __restrict__ boff) {
    __shared__ int s[512];
    int t = threadIdx.x;
    s[t] = (t < NB) ? bsum[t] : 0;
    for (int off = 1; off < 512; off <<= 1) {
        __syncthreads();
        int v = (t >= off) ? s[t - off] : 0;
        __syncthreads();
        s[t] += v;
    }
    __syncthreads();
    if (t < NB) boff[t] = s[t] - bsum[t];  // exclusive
}

// ---- scan stage 3: block-local exclusive scan + offset -> rowptr & pos ----
__global__ __launch_bounds__(256) void k_rowptr(const int* __restrict__ deg, const int* __restrict__ boff,
                                                int* __restrict__ rowptr, int* __restrict__ pos) {
    __shared__ int s[256];
    int t = threadIdx.x;
    int i = blockIdx.x * 256 + t;
    int v = (i < NN) ? deg[i] : 0;
    s[t] = v;
    for (int off = 1; off < 256; off <<= 1) {
        __syncthreads();
        int u = (t >= off) ? s[t - off] : 0;
        __syncthreads();
        s[t] += u;
    }
    __syncthreads();
    if (i < NN) {
        int r = boff[blockIdx.x] + s[t] - v;  // exclusive
        rowptr[i] = r;
        pos[i] = r;
    }
    if (i == 0) rowptr[NN] = ET;
}

// ---- bucket-fill src indices by dst ----
__global__ __launch_bounds__(256) void k_fill(const int* __restrict__ src32, const int* __restrict__ dst32,
                                              int* __restrict__ pos, int* __restrict__ src_sorted) {
    int t = blockIdx.x * 256 + threadIdx.x;
    if (t < ET) {
        int d = dst32[t];
        int slot = atomicAdd(&pos[d], 1);
        src_sorted[slot] = src32[t];
    }
}

// ---- layer 1: pull-agg (1 feat) + linear 1->32 + relu, group-per-node ----
__global__ __launch_bounds__(256) void k_pull1(const int* __restrict__ rowptr, const int* __restrict__ src_sorted,
                                               const float* __restrict__ x0, const float* __restrict__ W1,
                                               const float* __restrict__ b1, float* __restrict__ hout) {
    int g = (blockIdx.x * 256 + threadIdx.x) >> 5;
    if (g >= NN) return;
    int j = threadIdx.x & 31;
    int e0 = rowptr[g], e1 = rowptr[g + 1];
    float a0 = 0.f, a1 = 0.f, a2 = 0.f, a3 = 0.f;
    int e = e0;
    for (; e + 4 <= e1; e += 4) {
        int s0 = src_sorted[e], s1 = src_sorted[e + 1], s2 = src_sorted[e + 2], s3 = src_sorted[e + 3];
        a0 += x0[s0]; a1 += x0[s1]; a2 += x0[s2]; a3 += x0[s3];
    }
    for (; e < e1; ++e) a0 += x0[src_sorted[e]];
    float s = x0[g] + ((a0 + a1) + (a2 + a3));
    hout[(size_t)g * 32 + j] = fmaxf(fmaf(s, W1[j], b1[j]), 0.f);
}

// ---- fused pull-agg (32 feat) + 32x32 matmul (+relu), group-per-node, 4-deep ILP ----
template <int RELU>
__global__ __launch_bounds__(256) void k_agg_mm(const int* __restrict__ rowptr, const int* __restrict__ src_sorted,
                                                const float* __restrict__ hin, const float* __restrict__ W,
                                                const float* __restrict__ b, float* __restrict__ hout) {
    int g = (blockIdx.x * 256 + threadIdx.x) >> 5;
    if (g >= NN) return;
    int j = threadIdx.x & 31;
    int e0 = rowptr[g], e1 = rowptr[g + 1];
    float a0 = hin[(size_t)g * 32 + j], a1 = 0.f, a2 = 0.f, a3 = 0.f;
    int e = e0;
    for (; e + 4 <= e1; e += 4) {
        int s0 = src_sorted[e], s1 = src_sorted[e + 1], s2 = src_sorted[e + 2], s3 = src_sorted[e + 3];
        a0 += hin[(size_t)s0 * 32 + j];
        a1 += hin[(size_t)s1 * 32 + j];
        a2 += hin[(size_t)s2 * 32 + j];
        a3 += hin[(size_t)s3 * 32 + j];
    }
    for (; e < e1; ++e) a0 += hin[(size_t)src_sorted[e] * 32 + j];
    float acc = (a0 + a1) + (a2 + a3);
    float o = b[j];
#pragma unroll
    for (int k = 0; k < 32; ++k) o = fmaf(__shfl(acc, k, 32), W[k * 32 + j], o);
    if (RELU) o = fmaxf(o, 0.f);
    hout[(size_t)g * 32 + j] = o;
}

// ---- per-edge MLP (concat 64 -> 32 prelu -> 2) + persistence-image partial sums ----
__global__ __launch_bounds__(256) void k_edge(const int* __restrict__ src32, const int* __restrict__ dst32,
                                              const float* __restrict__ x4,
                                              const float* __restrict__ W5, const float* __restrict__ b5,
                                              const float* __restrict__ W6, const float* __restrict__ b6,
                                              float* __restrict__ pd_out, float* __restrict__ partial) {
    int e = blockIdx.x * 256 + threadIdx.x;  // EE divisible by 256, no tail
    int s = src32[e], d = dst32[e];

    float acc[32];
#pragma unroll
    for (int j = 0; j < 32; ++j) acc[j] = b5[j];

    float xv[32];
    {
        const float4* p = reinterpret_cast<const float4*>(x4 + (size_t)s * 32);
#pragma unroll
        for (int u = 0; u < 8; ++u) {
            float4 q = p[u];
            xv[4 * u + 0] = q.x; xv[4 * u + 1] = q.y; xv[4 * u + 2] = q.z; xv[4 * u + 3] = q.w;
        }
    }
#pragma unroll 8
    for (int k = 0; k < 32; ++k) {
        float xk = xv[k];
#pragma unroll
        for (int j = 0; j < 32; ++j) acc[j] = fmaf(xk, W5[k * 32 + j], acc[j]);
    }
    {
        const float4* p = reinterpret_cast<const float4*>(x4 + (size_t)d * 32);
#pragma unroll
        for (int u = 0; u < 8; ++u) {
            float4 q = p[u];
            xv[4 * u + 0] = q.x; xv[4 * u + 1] = q.y; xv[4 * u + 2] = q.z; xv[4 * u + 3] = q.w;
        }
    }
#pragma unroll 8
    for (int k = 0; k < 32; ++k) {
        float xk = xv[k];
#pragma unroll
        for (int j = 0; j < 32; ++j) acc[j] = fmaf(xk, W5[(32 + k) * 32 + j], acc[j]);
    }

    float pd0 = b6[0], pd1 = b6[1];
#pragma unroll
    for (int j = 0; j < 32; ++j) {
        float hj = acc[j];
        hj = hj >= 0.f ? hj : 0.1f * hj;  // prelu
        pd0 = fmaf(hj, W6[2 * j + 0], pd0);
        pd1 = fmaf(hj, W6[2 * j + 1], pd1);
    }
    pd_out[2 * (size_t)e + 0] = pd0;
    pd_out[2 * (size_t)e + 1] = pd1;

    // persistence image contribution
    float pers = pd1 - pd0;
    const float inv = 3.5355339059327378f;  // 1/(0.2*sqrt(2))
    float cb[6], cp[6];
#pragma unroll
    for (int i = 0; i < 6; ++i) {
        float te = 0.2f * (float)i;
        cb[i] = 0.5f * (1.f + erff((te - pd0) * inv));
        cp[i] = 0.5f * (1.f + erff((te - pers) * inv));
    }

    int lane = threadIdx.x & 63;
    int wv = threadIdx.x >> 6;
    __shared__ float sacc[4][25];
#pragma unroll
    for (int i = 0; i < 5; ++i) {
#pragma unroll
        for (int jj = 0; jj < 5; ++jj) {
            float v = pers * (cb[i + 1] - cb[i]) * (cp[jj + 1] - cp[jj]);
            v += __shfl_down(v, 32);
            v += __shfl_down(v, 16);
            v += __shfl_down(v, 8);
            v += __shfl_down(v, 4);
            v += __shfl_down(v, 2);
            v += __shfl_down(v, 1);
            if (lane == 0) sacc[wv][i * 5 + jj] = v;
        }
    }
    __syncthreads();
    if (threadIdx.x < 25) {
        partial[(size_t)blockIdx.x * 25 + threadIdx.x] =
            sacc[0][threadIdx.x] + sacc[1][threadIdx.x] + sacc[2][threadIdx.x] + sacc[3][threadIdx.x];
    }
}

// ---- deterministic final reduction of block partials per bin ----
__global__ __launch_bounds__(256) void k_img(const float* __restrict__ partial, float* __restrict__ img) {
    int bin = blockIdx.x;  // 25 blocks
    float s = 0.f;
    for (int k = threadIdx.x; k < EE / 256; k += 256) s += partial[(size_t)k * 25 + bin];
    s += __shfl_down(s, 32);
    s += __shfl_down(s, 16);
    s += __shfl_down(s, 8);
    s += __shfl_down(s, 4);
    s += __shfl_down(s, 2);
    s += __shfl_down(s, 1);
    __shared__ float wsum[4];
    if ((threadIdx.x & 63) == 0) wsum[threadIdx.x >> 6] = s;
    __syncthreads();
    if (threadIdx.x == 0) img[bin] = wsum[0] + wsum[1] + wsum[2] + wsum[3];
}

extern "C" void kernel_launch(void* const* d_in, const int* in_sizes, int n_in,
                              void* d_out, int out_size, void* d_ws, size_t ws_size,
                              hipStream_t stream) {
    const float* x0 = (const float*)d_in[0];
    // Harness converts integer inputs to int32: edge_index0 is (2, ET) int32.
    const int* src32 = (const int*)d_in[1];
    const int* dst32 = src32 + ET;
    const float* W1 = (const float*)d_in[2];
    const float* b1 = (const float*)d_in[3];
    const float* W2 = (const float*)d_in[4];
    const float* b2 = (const float*)d_in[5];
    const float* W4 = (const float*)d_in[6];
    const float* b4 = (const float*)d_in[7];
    const float* W3 = (const float*)d_in[8];
    const float* b3 = (const float*)d_in[9];
    const float* W5 = (const float*)d_in[10];
    const float* b5 = (const float*)d_in[11];
    const float* W6 = (const float*)d_in[12];
    const float* b6 = (const float*)d_in[13];
    float* out = (float*)d_out;

    char* w = (char*)d_ws;
    int* deg = (int*)w;                             // NN
    int* rowptr = deg + NN;                         // NN+1
    int* pos = rowptr + NN + 1;                     // NN
    int* bsum = pos + NN;                           // NB
    int* boff = bsum + NB;                          // NB
    int* src_sorted = boff + NB;                    // ET
    float* bufA = (float*)(src_sorted + ET);        // NN*32
    float* bufB = bufA + (size_t)NN * 32;           // NN*32
    float* partial = bufB + (size_t)NN * 32;        // (EE/256)*25

    // ---- build CSR (dst-bucketed) ----
    k_zero<<<(NN + 255) / 256, 256, 0, stream>>>(deg, NN);
    k_hist<<<(ET + 255) / 256, 256, 0, stream>>>(dst32, deg);
    k_blocksum<<<NB, 256, 0, stream>>>(deg, bsum);
    k_scanb<<<1, 512, 0, stream>>>(bsum, boff);
    k_rowptr<<<NB, 256, 0, stream>>>(deg, boff, rowptr, pos);
    k_fill<<<(ET + 255) / 256, 256, 0, stream>>>(src32, dst32, pos, src_sorted);

    // ---- layer 1 (pull + 1->32 + relu) ----
    k_pull1<<<(NN * 32 + 255) / 256, 256, 0, stream>>>(rowptr, src_sorted, x0, W1, b1, bufA);
    // ---- layers 2-4: fused pull-agg + matmul ----
    k_agg_mm<1><<<(NN * 32 + 255) / 256, 256, 0, stream>>>(rowptr, src_sorted, bufA, W2, b2, bufB);
    k_agg_mm<1><<<(NN * 32 + 255) / 256, 256, 0, stream>>>(rowptr, src_sorted, bufB, W4, b4, bufA);
    k_agg_mm<0><<<(NN * 32 + 255) / 256, 256, 0, stream>>>(rowptr, src_sorted, bufA, W3, b3, bufB);

    // ---- edge MLP + persistence image ----
    k_edge<<<EE / 256, 256, 0, stream>>>(src32, dst32, bufB, W5, b5, W6, b6, out, partial);
    k_img<<<25, 256, 0, stream>>>(partial, out + 2 * (size_t)EE);
}

// Round 5
// 376.050 us; speedup vs baseline: 2.1699x; 1.3422x over previous
//
#include <hip/hip_runtime.h>
#include <hip/hip_bf16.h>
#include <math.h>

#define NN 100000
#define EE 1600000
#define ET 1700000   // E + N self-loops
#define HID 32

#define BKT_SHIFT 10
#define BKT_MASK 1023
#define NBKT 98            // ceil(NN / 1024)
#define EPB 4096           // edges per block in stage A
#define NBLK_A 416         // ceil(ET / EPB)

// ---- zero small int buffer ----
__global__ __launch_bounds__(128) void k_zero(int* __restrict__ p, int n) {
    int t = blockIdx.x * 128 + threadIdx.x;
    if (t < n) p[t] = 0;
}

// ---- stage A0: coarse bucket counts (LDS hist, one global atomic per block-bin) ----
__global__ __launch_bounds__(256) void k_bkt_count(const int* __restrict__ dst32, int* __restrict__ bucket_cnt) {
    __shared__ int h[NBKT];
    for (int i = threadIdx.x; i < NBKT; i += 256) h[i] = 0;
    __syncthreads();
    int base = blockIdx.x * EPB;
    for (int k = 0; k < EPB; k += 256) {
        int t = base + k + threadIdx.x;
        if (t < ET) atomicAdd(&h[dst32[t] >> BKT_SHIFT], 1);
    }
    __syncthreads();
    for (int i = threadIdx.x; i < NBKT; i += 256) {
        int c = h[i];
        if (c) atomicAdd(&bucket_cnt[i], c);
    }
}

// ---- stage A scan: exclusive scan of 98 bucket counts ----
__global__ __launch_bounds__(128) void k_bkt_scan(const int* __restrict__ bucket_cnt, int* __restrict__ bucket_base,
                                                  int* __restrict__ bucket_fill) {
    __shared__ int s[128];
    int t = threadIdx.x;
    int v = (t < NBKT) ? bucket_cnt[t] : 0;
    s[t] = v;
    for (int off = 1; off < 128; off <<= 1) {
        __syncthreads();
        int u = (t >= off) ? s[t - off] : 0;
        __syncthreads();
        s[t] += u;
    }
    __syncthreads();
    int ex = s[t] - v;
    if (t < NBKT) {
        bucket_base[t] = ex;
        bucket_fill[t] = ex;
    }
    if (t == 0) bucket_base[NBKT] = ET;
}

// ---- stage A1: scatter (src,dst) pairs into coarse bucket regions, long sequential runs ----
__global__ __launch_bounds__(256) void k_bkt_scatter(const int* __restrict__ src32, const int* __restrict__ dst32,
                                                     int* __restrict__ bucket_fill, int2* __restrict__ pairs) {
    __shared__ int h[NBKT];
    __shared__ int bbase[NBKT];
    for (int i = threadIdx.x; i < NBKT; i += 256) h[i] = 0;
    __syncthreads();
    int base = blockIdx.x * EPB;
    for (int k = 0; k < EPB; k += 256) {
        int t = base + k + threadIdx.x;
        if (t < ET) atomicAdd(&h[dst32[t] >> BKT_SHIFT], 1);
    }
    __syncthreads();
    for (int i = threadIdx.x; i < NBKT; i += 256) {
        int c = h[i];
        bbase[i] = c ? atomicAdd(&bucket_fill[i], c) : 0;
        h[i] = 0;  // becomes local fill counter (same thread owns bin -> no race)
    }
    __syncthreads();
    for (int k = 0; k < EPB; k += 256) {
        int t = base + k + threadIdx.x;
        if (t < ET) {
            int sv = src32[t], dv = dst32[t];
            int b = dv >> BKT_SHIFT;
            int off = atomicAdd(&h[b], 1);
            pairs[bbase[b] + off] = make_int2(sv, dv);
        }
    }
}

// ---- stage B: per-bucket fine CSR (1024 nodes in LDS) + in-bucket scatter of src ----
__global__ __launch_bounds__(512) void k_bkt_csr(const int2* __restrict__ pairs, const int* __restrict__ bucket_base,
                                                 int* __restrict__ rowptr, int* __restrict__ src_sorted) {
    __shared__ int h[1024];
    __shared__ int tmp[512];
    int t = threadIdx.x;
    int b = blockIdx.x;
    int e0 = bucket_base[b], e1 = bucket_base[b + 1];
    int node0 = b << BKT_SHIFT;

    h[t] = 0;
    h[t + 512] = 0;
    __syncthreads();
    for (int e = e0 + t; e < e1; e += 512) atomicAdd(&h[pairs[e].y & BKT_MASK], 1);
    __syncthreads();

    // exclusive scan of 1024 bins with 512 threads (2 bins each)
    int i0 = 2 * t, i1 = 2 * t + 1;
    int v0 = h[i0], v1 = h[i1];
    int s = v0 + v1;
    tmp[t] = s;
    for (int off = 1; off < 512; off <<= 1) {
        __syncthreads();
        int u = (t >= off) ? tmp[t - off] : 0;
        __syncthreads();
        tmp[t] += u;
    }
    __syncthreads();
    int excl = tmp[t] - s;
    h[i0] = excl;
    h[i1] = excl + v0;
    __syncthreads();

    // rowptr for this bucket's nodes
    for (int i = t; i < 1024; i += 512) {
        int node = node0 + i;
        if (node < NN) rowptr[node] = e0 + h[i];
    }
    if (b == 0 && t == 0) rowptr[NN] = ET;
    __syncthreads();

    // scatter src into bucket-local (L2-resident) region
    for (int e = e0 + t; e < e1; e += 512) {
        int2 p = pairs[e];
        int sl = atomicAdd(&h[p.y & BKT_MASK], 1);
        src_sorted[e0 + sl] = p.x;
    }
}

// ---- layer 1: pull-agg (1 feat) + linear 1->32 + relu, group-per-node ----
__global__ __launch_bounds__(256) void k_pull1(const int* __restrict__ rowptr, const int* __restrict__ src_sorted,
                                               const float* __restrict__ x0, const float* __restrict__ W1,
                                               const float* __restrict__ b1, float* __restrict__ hout) {
    int g = (blockIdx.x * 256 + threadIdx.x) >> 5;
    if (g >= NN) return;
    int j = threadIdx.x & 31;
    int e0 = rowptr[g], e1 = rowptr[g + 1];
    float a0 = 0.f, a1 = 0.f, a2 = 0.f, a3 = 0.f;
    int e = e0;
    for (; e + 4 <= e1; e += 4) {
        int s0 = src_sorted[e], s1 = src_sorted[e + 1], s2 = src_sorted[e + 2], s3 = src_sorted[e + 3];
        a0 += x0[s0]; a1 += x0[s1]; a2 += x0[s2]; a3 += x0[s3];
    }
    for (; e < e1; ++e) a0 += x0[src_sorted[e]];
    float sv = x0[g] + ((a0 + a1) + (a2 + a3));
    hout[(size_t)g * 32 + j] = fmaxf(fmaf(sv, W1[j], b1[j]), 0.f);
}

// ---- fused pull-agg (32 feat) + 32x32 matmul (+relu), group-per-node, 4-deep ILP ----
template <int RELU>
__global__ __launch_bounds__(256) void k_agg_mm(const int* __restrict__ rowptr, const int* __restrict__ src_sorted,
                                                const float* __restrict__ hin, const float* __restrict__ W,
                                                const float* __restrict__ b, float* __restrict__ hout) {
    int g = (blockIdx.x * 256 + threadIdx.x) >> 5;
    if (g >= NN) return;
    int j = threadIdx.x & 31;
    int e0 = rowptr[g], e1 = rowptr[g + 1];
    float a0 = hin[(size_t)g * 32 + j], a1 = 0.f, a2 = 0.f, a3 = 0.f;
    int e = e0;
    for (; e + 4 <= e1; e += 4) {
        int s0 = src_sorted[e], s1 = src_sorted[e + 1], s2 = src_sorted[e + 2], s3 = src_sorted[e + 3];
        a0 += hin[(size_t)s0 * 32 + j];
        a1 += hin[(size_t)s1 * 32 + j];
        a2 += hin[(size_t)s2 * 32 + j];
        a3 += hin[(size_t)s3 * 32 + j];
    }
    for (; e < e1; ++e) a0 += hin[(size_t)src_sorted[e] * 32 + j];
    float acc = (a0 + a1) + (a2 + a3);
    float o = b[j];
#pragma unroll
    for (int k = 0; k < 32; ++k) o = fmaf(__shfl(acc, k, 32), W[k * 32 + j], o);
    if (RELU) o = fmaxf(o, 0.f);
    hout[(size_t)g * 32 + j] = o;
}

// ---- per-edge MLP (concat 64 -> 32 prelu -> 2) + persistence-image partial sums ----
__global__ __launch_bounds__(256) void k_edge(const int* __restrict__ src32, const int* __restrict__ dst32,
                                              const float* __restrict__ x4,
                                              const float* __restrict__ W5, const float* __restrict__ b5,
                                              const float* __restrict__ W6, const float* __restrict__ b6,
                                              float* __restrict__ pd_out, float* __restrict__ partial) {
    int e = blockIdx.x * 256 + threadIdx.x;  // EE divisible by 256, no tail
    int s = src32[e], d = dst32[e];

    float acc[32];
#pragma unroll
    for (int j = 0; j < 32; ++j) acc[j] = b5[j];

    float xv[32];
    {
        const float4* p = reinterpret_cast<const float4*>(x4 + (size_t)s * 32);
#pragma unroll
        for (int u = 0; u < 8; ++u) {
            float4 q = p[u];
            xv[4 * u + 0] = q.x; xv[4 * u + 1] = q.y; xv[4 * u + 2] = q.z; xv[4 * u + 3] = q.w;
        }
    }
#pragma unroll 8
    for (int k = 0; k < 32; ++k) {
        float xk = xv[k];
#pragma unroll
        for (int j = 0; j < 32; ++j) acc[j] = fmaf(xk, W5[k * 32 + j], acc[j]);
    }
    {
        const float4* p = reinterpret_cast<const float4*>(x4 + (size_t)d * 32);
#pragma unroll
        for (int u = 0; u < 8; ++u) {
            float4 q = p[u];
            xv[4 * u + 0] = q.x; xv[4 * u + 1] = q.y; xv[4 * u + 2] = q.z; xv[4 * u + 3] = q.w;
        }
    }
#pragma unroll 8
    for (int k = 0; k < 32; ++k) {
        float xk = xv[k];
#pragma unroll
        for (int j = 0; j < 32; ++j) acc[j] = fmaf(xk, W5[(32 + k) * 32 + j], acc[j]);
    }

    float pd0 = b6[0], pd1 = b6[1];
#pragma unroll
    for (int j = 0; j < 32; ++j) {
        float hj = acc[j];
        hj = hj >= 0.f ? hj : 0.1f * hj;  // prelu
        pd0 = fmaf(hj, W6[2 * j + 0], pd0);
        pd1 = fmaf(hj, W6[2 * j + 1], pd1);
    }
    pd_out[2 * (size_t)e + 0] = pd0;
    pd_out[2 * (size_t)e + 1] = pd1;

    // persistence image contribution
    float pers = pd1 - pd0;
    const float inv = 3.5355339059327378f;  // 1/(0.2*sqrt(2))
    float cb[6], cp[6];
#pragma unroll
    for (int i = 0; i < 6; ++i) {
        float te = 0.2f * (float)i;
        cb[i] = 0.5f * (1.f + erff((te - pd0) * inv));
        cp[i] = 0.5f * (1.f + erff((te - pers) * inv));
    }

    int lane = threadIdx.x & 63;
    int wv = threadIdx.x >> 6;
    __shared__ float sacc[4][25];
#pragma unroll
    for (int i = 0; i < 5; ++i) {
#pragma unroll
        for (int jj = 0; jj < 5; ++jj) {
            float v = pers * (cb[i + 1] - cb[i]) * (cp[jj + 1] - cp[jj]);
            v += __shfl_down(v, 32);
            v += __shfl_down(v, 16);
            v += __shfl_down(v, 8);
            v += __shfl_down(v, 4);
            v += __shfl_down(v, 2);
            v += __shfl_down(v, 1);
            if (lane == 0) sacc[wv][i * 5 + jj] = v;
        }
    }
    __syncthreads();
    if (threadIdx.x < 25) {
        partial[(size_t)blockIdx.x * 25 + threadIdx.x] =
            sacc[0][threadIdx.x] + sacc[1][threadIdx.x] + sacc[2][threadIdx.x] + sacc[3][threadIdx.x];
    }
}

// ---- deterministic final reduction of block partials per bin ----
__global__ __launch_bounds__(256) void k_img(const float* __restrict__ partial, float* __restrict__ img) {
    int bin = blockIdx.x;  // 25 blocks
    float s = 0.f;
    for (int k = threadIdx.x; k < EE / 256; k += 256) s += partial[(size_t)k * 25 + bin];
    s += __shfl_down(s, 32);
    s += __shfl_down(s, 16);
    s += __shfl_down(s, 8);
    s += __shfl_down(s, 4);
    s += __shfl_down(s, 2);
    s += __shfl_down(s, 1);
    __shared__ float wsum[4];
    if ((threadIdx.x & 63) == 0) wsum[threadIdx.x >> 6] = s;
    __syncthreads();
    if (threadIdx.x == 0) img[bin] = wsum[0] + wsum[1] + wsum[2] + wsum[3];
}

extern "C" void kernel_launch(void* const* d_in, const int* in_sizes, int n_in,
                              void* d_out, int out_size, void* d_ws, size_t ws_size,
                              hipStream_t stream) {
    const float* x0 = (const float*)d_in[0];
    // Harness converts integer inputs to int32: edge_index0 is (2, ET) int32.
    const int* src32 = (const int*)d_in[1];
    const int* dst32 = src32 + ET;
    const float* W1 = (const float*)d_in[2];
    const float* b1 = (const float*)d_in[3];
    const float* W2 = (const float*)d_in[4];
    const float* b2 = (const float*)d_in[5];
    const float* W4 = (const float*)d_in[6];
    const float* b4 = (const float*)d_in[7];
    const float* W3 = (const float*)d_in[8];
    const float* b3 = (const float*)d_in[9];
    const float* W5 = (const float*)d_in[10];
    const float* b5 = (const float*)d_in[11];
    const float* W6 = (const float*)d_in[12];
    const float* b6 = (const float*)d_in[13];
    float* out = (float*)d_out;

    char* w = (char*)d_ws;
    int2* pairs = (int2*)w;                          // ET int2 (8B aligned at base)
    int* bucket_cnt = (int*)(pairs + ET);            // NBKT
    int* bucket_base = bucket_cnt + NBKT;            // NBKT+1
    int* bucket_fill = bucket_base + NBKT + 1;       // NBKT
    int* rowptr = bucket_fill + NBKT;                // NN+1
    int* src_sorted = rowptr + NN + 1;               // ET
    float* bufA = (float*)(src_sorted + ET);         // NN*32
    float* bufB = bufA + (size_t)NN * 32;            // NN*32
    float* partial = bufB + (size_t)NN * 32;         // (EE/256)*25

    // ---- build CSR via coarse-bucket counting sort ----
    k_zero<<<1, 128, 0, stream>>>(bucket_cnt, NBKT);
    k_bkt_count<<<NBLK_A, 256, 0, stream>>>(dst32, bucket_cnt);
    k_bkt_scan<<<1, 128, 0, stream>>>(bucket_cnt, bucket_base, bucket_fill);
    k_bkt_scatter<<<NBLK_A, 256, 0, stream>>>(src32, dst32, bucket_fill, pairs);
    k_bkt_csr<<<NBKT, 512, 0, stream>>>(pairs, bucket_base, rowptr, src_sorted);

    // ---- layer 1 (pull + 1->32 + relu) ----
    k_pull1<<<(NN * 32 + 255) / 256, 256, 0, stream>>>(rowptr, src_sorted, x0, W1, b1, bufA);
    // ---- layers 2-4: fused pull-agg + matmul ----
    k_agg_mm<1><<<(NN * 32 + 255) / 256, 256, 0, stream>>>(rowptr, src_sorted, bufA, W2, b2, bufB);
    k_agg_mm<1><<<(NN * 32 + 255) / 256, 256, 0, stream>>>(rowptr, src_sorted, bufB, W4, b4, bufA);
    k_agg_mm<0><<<(NN * 32 + 255) / 256, 256, 0, stream>>>(rowptr, src_sorted, bufA, W3, b3, bufB);

    // ---- edge MLP + persistence image ----
    k_edge<<<EE / 256, 256, 0, stream>>>(src32, dst32, bufB, W5, b5, W6, b6, out, partial);
    k_img<<<25, 256, 0, stream>>>(partial, out + 2 * (size_t)EE);
}

// Round 6
// 355.142 us; speedup vs baseline: 2.2976x; 1.0589x over previous
//
#include <hip/hip_runtime.h>
#include <hip/hip_bf16.h>
#include <hip/hip_fp16.h>
#include <math.h>

#define NN 100000
#define EE 1600000
#define ET 1700000   // E + N self-loops
#define HID 32

#define BKT_SHIFT 10
#define BKT_MASK 1023
#define NBKT 98            // ceil(NN / 1024)
#define EPB 4096           // edges per block in stage A
#define NBLK_A 416         // ceil(ET / EPB)

// ---- zero small int buffer ----
__global__ __launch_bounds__(128) void k_zero(int* __restrict__ p, int n) {
    int t = blockIdx.x * 128 + threadIdx.x;
    if (t < n) p[t] = 0;
}

// ---- stage A0: coarse bucket counts (LDS hist, one global atomic per block-bin) ----
__global__ __launch_bounds__(256) void k_bkt_count(const int* __restrict__ dst32, int* __restrict__ bucket_cnt) {
    __shared__ int h[NBKT];
    for (int i = threadIdx.x; i < NBKT; i += 256) h[i] = 0;
    __syncthreads();
    int base = blockIdx.x * EPB;
    for (int k = 0; k < EPB; k += 256) {
        int t = base + k + threadIdx.x;
        if (t < ET) atomicAdd(&h[dst32[t] >> BKT_SHIFT], 1);
    }
    __syncthreads();
    for (int i = threadIdx.x; i < NBKT; i += 256) {
        int c = h[i];
        if (c) atomicAdd(&bucket_cnt[i], c);
    }
}

// ---- stage A scan: exclusive scan of 98 bucket counts ----
__global__ __launch_bounds__(128) void k_bkt_scan(const int* __restrict__ bucket_cnt, int* __restrict__ bucket_base,
                                                  int* __restrict__ bucket_fill) {
    __shared__ int s[128];
    int t = threadIdx.x;
    int v = (t < NBKT) ? bucket_cnt[t] : 0;
    s[t] = v;
    for (int off = 1; off < 128; off <<= 1) {
        __syncthreads();
        int u = (t >= off) ? s[t - off] : 0;
        __syncthreads();
        s[t] += u;
    }
    __syncthreads();
    int ex = s[t] - v;
    if (t < NBKT) {
        bucket_base[t] = ex;
        bucket_fill[t] = ex;
    }
    if (t == 0) bucket_base[NBKT] = ET;
}

// ---- stage A1: scatter (src,dst) pairs into coarse bucket regions, long sequential runs ----
__global__ __launch_bounds__(256) void k_bkt_scatter(const int* __restrict__ src32, const int* __restrict__ dst32,
                                                     int* __restrict__ bucket_fill, int2* __restrict__ pairs) {
    __shared__ int h[NBKT];
    __shared__ int bbase[NBKT];
    for (int i = threadIdx.x; i < NBKT; i += 256) h[i] = 0;
    __syncthreads();
    int base = blockIdx.x * EPB;
    for (int k = 0; k < EPB; k += 256) {
        int t = base + k + threadIdx.x;
        if (t < ET) atomicAdd(&h[dst32[t] >> BKT_SHIFT], 1);
    }
    __syncthreads();
    for (int i = threadIdx.x; i < NBKT; i += 256) {
        int c = h[i];
        bbase[i] = c ? atomicAdd(&bucket_fill[i], c) : 0;
        h[i] = 0;  // becomes local fill counter (same thread owns bin -> no race)
    }
    __syncthreads();
    for (int k = 0; k < EPB; k += 256) {
        int t = base + k + threadIdx.x;
        if (t < ET) {
            int sv = src32[t], dv = dst32[t];
            int b = dv >> BKT_SHIFT;
            int off = atomicAdd(&h[b], 1);
            pairs[bbase[b] + off] = make_int2(sv, dv);
        }
    }
}

// ---- stage B: per-bucket fine CSR (1024 nodes in LDS) + in-bucket scatter of src ----
__global__ __launch_bounds__(512) void k_bkt_csr(const int2* __restrict__ pairs, const int* __restrict__ bucket_base,
                                                 int* __restrict__ rowptr, int* __restrict__ src_sorted) {
    __shared__ int h[1024];
    __shared__ int tmp[512];
    int t = threadIdx.x;
    int b = blockIdx.x;
    int e0 = bucket_base[b], e1 = bucket_base[b + 1];
    int node0 = b << BKT_SHIFT;

    h[t] = 0;
    h[t + 512] = 0;
    __syncthreads();
    for (int e = e0 + t; e < e1; e += 512) atomicAdd(&h[pairs[e].y & BKT_MASK], 1);
    __syncthreads();

    // exclusive scan of 1024 bins with 512 threads (2 bins each)
    int i0 = 2 * t, i1 = 2 * t + 1;
    int v0 = h[i0], v1 = h[i1];
    int s = v0 + v1;
    tmp[t] = s;
    for (int off = 1; off < 512; off <<= 1) {
        __syncthreads();
        int u = (t >= off) ? tmp[t - off] : 0;
        __syncthreads();
        tmp[t] += u;
    }
    __syncthreads();
    int excl = tmp[t] - s;
    h[i0] = excl;
    h[i1] = excl + v0;
    __syncthreads();

    // rowptr for this bucket's nodes
    for (int i = t; i < 1024; i += 512) {
        int node = node0 + i;
        if (node < NN) rowptr[node] = e0 + h[i];
    }
    if (b == 0 && t == 0) rowptr[NN] = ET;
    __syncthreads();

    // scatter src into bucket-local (L2-resident) region
    for (int e = e0 + t; e < e1; e += 512) {
        int2 p = pairs[e];
        int sl = atomicAdd(&h[p.y & BKT_MASK], 1);
        src_sorted[e0 + sl] = p.x;
    }
}

// ---- layer 1: pull-agg (1 feat) + linear 1->32 + relu, group-per-node ----
__global__ __launch_bounds__(256) void k_pull1(const int* __restrict__ rowptr, const int* __restrict__ src_sorted,
                                               const float* __restrict__ x0, const float* __restrict__ W1,
                                               const float* __restrict__ b1, float* __restrict__ hout) {
    int g = (blockIdx.x * 256 + threadIdx.x) >> 5;
    if (g >= NN) return;
    int j = threadIdx.x & 31;
    int e0 = rowptr[g], e1 = rowptr[g + 1];
    float a0 = 0.f, a1 = 0.f, a2 = 0.f, a3 = 0.f;
    int e = e0;
    for (; e + 4 <= e1; e += 4) {
        int s0 = src_sorted[e], s1 = src_sorted[e + 1], s2 = src_sorted[e + 2], s3 = src_sorted[e + 3];
        a0 += x0[s0]; a1 += x0[s1]; a2 += x0[s2]; a3 += x0[s3];
    }
    for (; e < e1; ++e) a0 += x0[src_sorted[e]];
    float sv = x0[g] + ((a0 + a1) + (a2 + a3));
    hout[(size_t)g * 32 + j] = fmaxf(fmaf(sv, W1[j], b1[j]), 0.f);
}

// ---- fused pull-agg (32 feat) + 32x32 matmul (+relu), group-per-node, 4-deep ILP ----
template <int RELU>
__global__ __launch_bounds__(256) void k_agg_mm(const int* __restrict__ rowptr, const int* __restrict__ src_sorted,
                                                const float* __restrict__ hin, const float* __restrict__ W,
                                                const float* __restrict__ b, float* __restrict__ hout) {
    int g = (blockIdx.x * 256 + threadIdx.x) >> 5;
    if (g >= NN) return;
    int j = threadIdx.x & 31;
    int e0 = rowptr[g], e1 = rowptr[g + 1];
    float a0 = hin[(size_t)g * 32 + j], a1 = 0.f, a2 = 0.f, a3 = 0.f;
    int e = e0;
    for (; e + 4 <= e1; e += 4) {
        int s0 = src_sorted[e], s1 = src_sorted[e + 1], s2 = src_sorted[e + 2], s3 = src_sorted[e + 3];
        a0 += hin[(size_t)s0 * 32 + j];
        a1 += hin[(size_t)s1 * 32 + j];
        a2 += hin[(size_t)s2 * 32 + j];
        a3 += hin[(size_t)s3 * 32 + j];
    }
    for (; e < e1; ++e) a0 += hin[(size_t)src_sorted[e] * 32 + j];
    float acc = (a0 + a1) + (a2 + a3);
    float o = b[j];
#pragma unroll
    for (int k = 0; k < 32; ++k) o = fmaf(__shfl(acc, k, 32), W[k * 32 + j], o);
    if (RELU) o = fmaxf(o, 0.f);
    hout[(size_t)g * 32 + j] = o;
}

// ---- layer 4 fused: pull-agg + (W3,b3) matmul + per-node W5 projections -> u16 (b5 folded), v16 ----
__global__ __launch_bounds__(256) void k_agg_mm_proj(const int* __restrict__ rowptr, const int* __restrict__ src_sorted,
                                                     const float* __restrict__ hin, const float* __restrict__ W3,
                                                     const float* __restrict__ b3,
                                                     const float* __restrict__ W5, const float* __restrict__ b5,
                                                     __half* __restrict__ u16, __half* __restrict__ v16) {
    int g = (blockIdx.x * 256 + threadIdx.x) >> 5;
    if (g >= NN) return;
    int j = threadIdx.x & 31;
    int e0 = rowptr[g], e1 = rowptr[g + 1];
    float a0 = hin[(size_t)g * 32 + j], a1 = 0.f, a2 = 0.f, a3 = 0.f;
    int e = e0;
    for (; e + 4 <= e1; e += 4) {
        int s0 = src_sorted[e], s1 = src_sorted[e + 1], s2 = src_sorted[e + 2], s3 = src_sorted[e + 3];
        a0 += hin[(size_t)s0 * 32 + j];
        a1 += hin[(size_t)s1 * 32 + j];
        a2 += hin[(size_t)s2 * 32 + j];
        a3 += hin[(size_t)s3 * 32 + j];
    }
    for (; e < e1; ++e) a0 += hin[(size_t)src_sorted[e] * 32 + j];
    float acc = (a0 + a1) + (a2 + a3);
    // x4_j = agg . W3[:,j] + b3[j]   (no relu on layer 4)
    float o = b3[j];
#pragma unroll
    for (int k = 0; k < 32; ++k) o = fmaf(__shfl(acc, k, 32), W3[k * 32 + j], o);
    // u_j = x4 . W5[0:32, j] + b5[j] ; v_j = x4 . W5[32:64, j]
    float u = b5[j], v = 0.f;
#pragma unroll
    for (int k = 0; k < 32; ++k) {
        float xk = __shfl(o, k, 32);
        u = fmaf(xk, W5[k * 32 + j], u);
        v = fmaf(xk, W5[(32 + k) * 32 + j], v);
    }
    u16[(size_t)g * 32 + j] = __float2half_rn(u);
    v16[(size_t)g * 32 + j] = __float2half_rn(v);
}

// ---- per-edge: h = prelu(u[s]+v[d]) ; pd = h.W6 + b6 ; persistence-image partials ----
__global__ __launch_bounds__(256) void k_edge(const int* __restrict__ src32, const int* __restrict__ dst32,
                                              const __half* __restrict__ u16, const __half* __restrict__ v16,
                                              const float* __restrict__ W6, const float* __restrict__ b6,
                                              float* __restrict__ pd_out, float* __restrict__ partial) {
    int e = blockIdx.x * 256 + threadIdx.x;  // EE divisible by 256, no tail
    int s = src32[e], d = dst32[e];

    const uint4* pu = reinterpret_cast<const uint4*>(u16 + (size_t)s * 32);
    const uint4* pv = reinterpret_cast<const uint4*>(v16 + (size_t)d * 32);

    float pd0 = b6[0], pd1 = b6[1];
#pragma unroll
    for (int q = 0; q < 4; ++q) {
        uint4 ua = pu[q];
        uint4 vb = pv[q];
        const __half2* ah = reinterpret_cast<const __half2*>(&ua);
        const __half2* bh = reinterpret_cast<const __half2*>(&vb);
#pragma unroll
        for (int r = 0; r < 4; ++r) {
            float2 f = __half22float2(__hadd2(ah[r], bh[r]));
            int j = q * 8 + 2 * r;
            float h0 = f.x >= 0.f ? f.x : 0.1f * f.x;
            float h1 = f.y >= 0.f ? f.y : 0.1f * f.y;
            pd0 = fmaf(h0, W6[2 * j + 0], pd0);
            pd1 = fmaf(h0, W6[2 * j + 1], pd1);
            pd0 = fmaf(h1, W6[2 * (j + 1) + 0], pd0);
            pd1 = fmaf(h1, W6[2 * (j + 1) + 1], pd1);
        }
    }
    pd_out[2 * (size_t)e + 0] = pd0;
    pd_out[2 * (size_t)e + 1] = pd1;

    // persistence image contribution
    float pers = pd1 - pd0;
    const float inv = 3.5355339059327378f;  // 1/(0.2*sqrt(2))
    float cb[6], cp[6];
#pragma unroll
    for (int i = 0; i < 6; ++i) {
        float te = 0.2f * (float)i;
        cb[i] = 0.5f * (1.f + erff((te - pd0) * inv));
        cp[i] = 0.5f * (1.f + erff((te - pers) * inv));
    }

    int lane = threadIdx.x & 63;
    int wv = threadIdx.x >> 6;
    __shared__ float sacc[4][25];
#pragma unroll
    for (int i = 0; i < 5; ++i) {
#pragma unroll
        for (int jj = 0; jj < 5; ++jj) {
            float v = pers * (cb[i + 1] - cb[i]) * (cp[jj + 1] - cp[jj]);
            v += __shfl_down(v, 32);
            v += __shfl_down(v, 16);
            v += __shfl_down(v, 8);
            v += __shfl_down(v, 4);
            v += __shfl_down(v, 2);
            v += __shfl_down(v, 1);
            if (lane == 0) sacc[wv][i * 5 + jj] = v;
        }
    }
    __syncthreads();
    if (threadIdx.x < 25) {
        partial[(size_t)blockIdx.x * 25 + threadIdx.x] =
            sacc[0][threadIdx.x] + sacc[1][threadIdx.x] + sacc[2][threadIdx.x] + sacc[3][threadIdx.x];
    }
}

// ---- deterministic final reduction of block partials per bin ----
__global__ __launch_bounds__(256) void k_img(const float* __restrict__ partial, float* __restrict__ img) {
    int bin = blockIdx.x;  // 25 blocks
    float s = 0.f;
    for (int k = threadIdx.x; k < EE / 256; k += 256) s += partial[(size_t)k * 25 + bin];
    s += __shfl_down(s, 32);
    s += __shfl_down(s, 16);
    s += __shfl_down(s, 8);
    s += __shfl_down(s, 4);
    s += __shfl_down(s, 2);
    s += __shfl_down(s, 1);
    __shared__ float wsum[4];
    if ((threadIdx.x & 63) == 0) wsum[threadIdx.x >> 6] = s;
    __syncthreads();
    if (threadIdx.x == 0) img[bin] = wsum[0] + wsum[1] + wsum[2] + wsum[3];
}

extern "C" void kernel_launch(void* const* d_in, const int* in_sizes, int n_in,
                              void* d_out, int out_size, void* d_ws, size_t ws_size,
                              hipStream_t stream) {
    const float* x0 = (const float*)d_in[0];
    // Harness converts integer inputs to int32: edge_index0 is (2, ET) int32.
    const int* src32 = (const int*)d_in[1];
    const int* dst32 = src32 + ET;
    const float* W1 = (const float*)d_in[2];
    const float* b1 = (const float*)d_in[3];
    const float* W2 = (const float*)d_in[4];
    const float* b2 = (const float*)d_in[5];
    const float* W4 = (const float*)d_in[6];
    const float* b4 = (const float*)d_in[7];
    const float* W3 = (const float*)d_in[8];
    const float* b3 = (const float*)d_in[9];
    const float* W5 = (const float*)d_in[10];
    const float* b5 = (const float*)d_in[11];
    const float* W6 = (const float*)d_in[12];
    const float* b6 = (const float*)d_in[13];
    float* out = (float*)d_out;

    char* w = (char*)d_ws;
    int2* pairs = (int2*)w;                          // ET int2
    int* bucket_cnt = (int*)(pairs + ET);            // NBKT
    int* bucket_base = bucket_cnt + NBKT;            // NBKT+1
    int* bucket_fill = bucket_base + NBKT + 1;       // NBKT
    int* rowptr = bucket_fill + NBKT;                // NN+1
    int* src_sorted = rowptr + NN + 1;               // ET
    float* bufA = (float*)(src_sorted + ET);         // NN*32
    float* bufB = bufA + (size_t)NN * 32;            // NN*32
    float* partial = bufB + (size_t)NN * 32;         // (EE/256)*25
    // u16/v16 alias bufB (free when layer-4 proj runs: it reads bufA)
    __half* u16 = (__half*)bufB;                     // NN*32 halfs
    __half* v16 = u16 + (size_t)NN * 32;             // NN*32 halfs

    // ---- build CSR via coarse-bucket counting sort ----
    k_zero<<<1, 128, 0, stream>>>(bucket_cnt, NBKT);
    k_bkt_count<<<NBLK_A, 256, 0, stream>>>(dst32, bucket_cnt);
    k_bkt_scan<<<1, 128, 0, stream>>>(bucket_cnt, bucket_base, bucket_fill);
    k_bkt_scatter<<<NBLK_A, 256, 0, stream>>>(src32, dst32, bucket_fill, pairs);
    k_bkt_csr<<<NBKT, 512, 0, stream>>>(pairs, bucket_base, rowptr, src_sorted);

    // ---- layer 1 (pull + 1->32 + relu) ----
    k_pull1<<<(NN * 32 + 255) / 256, 256, 0, stream>>>(rowptr, src_sorted, x0, W1, b1, bufA);
    // ---- layers 2-3: fused pull-agg + matmul ----
    k_agg_mm<1><<<(NN * 32 + 255) / 256, 256, 0, stream>>>(rowptr, src_sorted, bufA, W2, b2, bufB);
    k_agg_mm<1><<<(NN * 32 + 255) / 256, 256, 0, stream>>>(rowptr, src_sorted, bufB, W4, b4, bufA);
    // ---- layer 4 + per-node W5 projections (u,v in fp16) ----
    k_agg_mm_proj<<<(NN * 32 + 255) / 256, 256, 0, stream>>>(rowptr, src_sorted, bufA, W3, b3, W5, b5, u16, v16);

    // ---- edge MLP + persistence image ----
    k_edge<<<EE / 256, 256, 0, stream>>>(src32, dst32, u16, v16, W6, b6, out, partial);
    k_img<<<25, 256, 0, stream>>>(partial, out + 2 * (size_t)EE);
}

// Round 7
// 311.448 us; speedup vs baseline: 2.6200x; 1.1403x over previous
//
#include <hip/hip_runtime.h>
#include <hip/hip_bf16.h>
#include <hip/hip_fp16.h>
#include <math.h>

#define NN 100000
#define EE 1600000
#define ET 1700000   // E + N self-loops
#define HID 32

#define BKT_SHIFT 10
#define BKT_MASK 1023
#define NBKT 98            // ceil(NN / 1024)
#define EPB 4096           // edges per block in stage A
#define NBLK_A 416         // ceil(ET / EPB)

// ---- zero small int buffer ----
__global__ __launch_bounds__(128) void k_zero(int* __restrict__ p, int n) {
    int t = blockIdx.x * 128 + threadIdx.x;
    if (t < n) p[t] = 0;
}

// ---- stage A0: coarse bucket counts (LDS hist, one global atomic per block-bin) ----
__global__ __launch_bounds__(256) void k_bkt_count(const int* __restrict__ dst32, int* __restrict__ bucket_cnt) {
    __shared__ int h[NBKT];
    for (int i = threadIdx.x; i < NBKT; i += 256) h[i] = 0;
    __syncthreads();
    int base = blockIdx.x * EPB;
    for (int k = 0; k < EPB; k += 256) {
        int t = base + k + threadIdx.x;
        if (t < ET) atomicAdd(&h[dst32[t] >> BKT_SHIFT], 1);
    }
    __syncthreads();
    for (int i = threadIdx.x; i < NBKT; i += 256) {
        int c = h[i];
        if (c) atomicAdd(&bucket_cnt[i], c);
    }
}

// ---- stage A scan: exclusive scan of 98 bucket counts ----
__global__ __launch_bounds__(128) void k_bkt_scan(const int* __restrict__ bucket_cnt, int* __restrict__ bucket_base,
                                                  int* __restrict__ bucket_fill) {
    __shared__ int s[128];
    int t = threadIdx.x;
    int v = (t < NBKT) ? bucket_cnt[t] : 0;
    s[t] = v;
    for (int off = 1; off < 128; off <<= 1) {
        __syncthreads();
        int u = (t >= off) ? s[t - off] : 0;
        __syncthreads();
        s[t] += u;
    }
    __syncthreads();
    int ex = s[t] - v;
    if (t < NBKT) {
        bucket_base[t] = ex;
        bucket_fill[t] = ex;
    }
    if (t == 0) bucket_base[NBKT] = ET;
}

// ---- stage A1: scatter (src,dst) pairs into coarse bucket regions, long sequential runs ----
__global__ __launch_bounds__(256) void k_bkt_scatter(const int* __restrict__ src32, const int* __restrict__ dst32,
                                                     int* __restrict__ bucket_fill, int2* __restrict__ pairs) {
    __shared__ int h[NBKT];
    __shared__ int bbase[NBKT];
    for (int i = threadIdx.x; i < NBKT; i += 256) h[i] = 0;
    __syncthreads();
    int base = blockIdx.x * EPB;
    for (int k = 0; k < EPB; k += 256) {
        int t = base + k + threadIdx.x;
        if (t < ET) atomicAdd(&h[dst32[t] >> BKT_SHIFT], 1);
    }
    __syncthreads();
    for (int i = threadIdx.x; i < NBKT; i += 256) {
        int c = h[i];
        bbase[i] = c ? atomicAdd(&bucket_fill[i], c) : 0;
        h[i] = 0;  // becomes local fill counter (same thread owns bin -> no race)
    }
    __syncthreads();
    for (int k = 0; k < EPB; k += 256) {
        int t = base + k + threadIdx.x;
        if (t < ET) {
            int sv = src32[t], dv = dst32[t];
            int b = dv >> BKT_SHIFT;
            int off = atomicAdd(&h[b], 1);
            pairs[bbase[b] + off] = make_int2(sv, dv);
        }
    }
}

// ---- stage B: per-bucket fine CSR (1024 nodes in LDS) + in-bucket scatter of src ----
__global__ __launch_bounds__(512) void k_bkt_csr(const int2* __restrict__ pairs, const int* __restrict__ bucket_base,
                                                 int* __restrict__ rowptr, int* __restrict__ src_sorted) {
    __shared__ int h[1024];
    __shared__ int tmp[512];
    int t = threadIdx.x;
    int b = blockIdx.x;
    int e0 = bucket_base[b], e1 = bucket_base[b + 1];
    int node0 = b << BKT_SHIFT;

    h[t] = 0;
    h[t + 512] = 0;
    __syncthreads();
    for (int e = e0 + t; e < e1; e += 512) atomicAdd(&h[pairs[e].y & BKT_MASK], 1);
    __syncthreads();

    // exclusive scan of 1024 bins with 512 threads (2 bins each)
    int i0 = 2 * t, i1 = 2 * t + 1;
    int v0 = h[i0], v1 = h[i1];
    int s = v0 + v1;
    tmp[t] = s;
    for (int off = 1; off < 512; off <<= 1) {
        __syncthreads();
        int u = (t >= off) ? tmp[t - off] : 0;
        __syncthreads();
        tmp[t] += u;
    }
    __syncthreads();
    int excl = tmp[t] - s;
    h[i0] = excl;
    h[i1] = excl + v0;
    __syncthreads();

    // rowptr for this bucket's nodes
    for (int i = t; i < 1024; i += 512) {
        int node = node0 + i;
        if (node < NN) rowptr[node] = e0 + h[i];
    }
    if (b == 0 && t == 0) rowptr[NN] = ET;
    __syncthreads();

    // scatter src into bucket-local (L2-resident) region
    for (int e = e0 + t; e < e1; e += 512) {
        int2 p = pairs[e];
        int sl = atomicAdd(&h[p.y & BKT_MASK], 1);
        src_sorted[e0 + sl] = p.x;
    }
}

// ---- layer 1: pull-agg (1 feat) + linear 1->32 + relu, group-per-node, fp16 out ----
__global__ __launch_bounds__(256) void k_pull1(const int* __restrict__ rowptr, const int* __restrict__ src_sorted,
                                               const float* __restrict__ x0, const float* __restrict__ W1,
                                               const float* __restrict__ b1, __half* __restrict__ hout) {
    int g = (blockIdx.x * 256 + threadIdx.x) >> 5;
    if (g >= NN) return;
    int j = threadIdx.x & 31;
    int e0 = rowptr[g], e1 = rowptr[g + 1];
    float a0 = 0.f, a1 = 0.f, a2 = 0.f, a3 = 0.f;
    int e = e0;
    for (; e + 4 <= e1; e += 4) {
        int s0 = src_sorted[e], s1 = src_sorted[e + 1], s2 = src_sorted[e + 2], s3 = src_sorted[e + 3];
        a0 += x0[s0]; a1 += x0[s1]; a2 += x0[s2]; a3 += x0[s3];
    }
    for (; e < e1; ++e) a0 += x0[src_sorted[e]];
    float sv = x0[g] + ((a0 + a1) + (a2 + a3));
    hout[(g << 5) + j] = __float2half_rn(fmaxf(fmaf(sv, W1[j], b1[j]), 0.f));
}

// ---- fused pull-agg (32 feat, fp16 rows) + 32x32 matmul (+relu), 8-deep ILP ----
template <int RELU>
__global__ __launch_bounds__(256) void k_agg_mm(const int* __restrict__ rowptr, const int* __restrict__ src_sorted,
                                                const __half* __restrict__ hin, const float* __restrict__ W,
                                                const float* __restrict__ b, __half* __restrict__ hout) {
    int g = (blockIdx.x * 256 + threadIdx.x) >> 5;
    if (g >= NN) return;
    int j = threadIdx.x & 31;
    int e0 = rowptr[g], e1 = rowptr[g + 1];
    float a0 = __half2float(hin[(g << 5) + j]);
    float a1 = 0.f, a2 = 0.f, a3 = 0.f, a4 = 0.f, a5 = 0.f, a6 = 0.f, a7 = 0.f;
    int e = e0;
    for (; e + 8 <= e1; e += 8) {
        int s0 = src_sorted[e + 0], s1 = src_sorted[e + 1], s2 = src_sorted[e + 2], s3 = src_sorted[e + 3];
        int s4 = src_sorted[e + 4], s5 = src_sorted[e + 5], s6 = src_sorted[e + 6], s7 = src_sorted[e + 7];
        a0 += __half2float(hin[(s0 << 5) + j]);
        a1 += __half2float(hin[(s1 << 5) + j]);
        a2 += __half2float(hin[(s2 << 5) + j]);
        a3 += __half2float(hin[(s3 << 5) + j]);
        a4 += __half2float(hin[(s4 << 5) + j]);
        a5 += __half2float(hin[(s5 << 5) + j]);
        a6 += __half2float(hin[(s6 << 5) + j]);
        a7 += __half2float(hin[(s7 << 5) + j]);
    }
    for (; e < e1; ++e) a0 += __half2float(hin[(src_sorted[e] << 5) + j]);
    float acc = ((a0 + a1) + (a2 + a3)) + ((a4 + a5) + (a6 + a7));
    float o = b[j];
#pragma unroll
    for (int k = 0; k < 32; ++k) o = fmaf(__shfl(acc, k, 32), W[k * 32 + j], o);
    if (RELU) o = fmaxf(o, 0.f);
    hout[(g << 5) + j] = __float2half_rn(o);
}

// ---- layer 4 fused: pull-agg (fp16) + (W3,b3) matmul + per-node W5 projections -> u16,v16 ----
__global__ __launch_bounds__(256) void k_agg_mm_proj(const int* __restrict__ rowptr, const int* __restrict__ src_sorted,
                                                     const __half* __restrict__ hin, const float* __restrict__ W3,
                                                     const float* __restrict__ b3,
                                                     const float* __restrict__ W5, const float* __restrict__ b5,
                                                     __half* __restrict__ u16, __half* __restrict__ v16) {
    int g = (blockIdx.x * 256 + threadIdx.x) >> 5;
    if (g >= NN) return;
    int j = threadIdx.x & 31;
    int e0 = rowptr[g], e1 = rowptr[g + 1];
    float a0 = __half2float(hin[(g << 5) + j]);
    float a1 = 0.f, a2 = 0.f, a3 = 0.f, a4 = 0.f, a5 = 0.f, a6 = 0.f, a7 = 0.f;
    int e = e0;
    for (; e + 8 <= e1; e += 8) {
        int s0 = src_sorted[e + 0], s1 = src_sorted[e + 1], s2 = src_sorted[e + 2], s3 = src_sorted[e + 3];
        int s4 = src_sorted[e + 4], s5 = src_sorted[e + 5], s6 = src_sorted[e + 6], s7 = src_sorted[e + 7];
        a0 += __half2float(hin[(s0 << 5) + j]);
        a1 += __half2float(hin[(s1 << 5) + j]);
        a2 += __half2float(hin[(s2 << 5) + j]);
        a3 += __half2float(hin[(s3 << 5) + j]);
        a4 += __half2float(hin[(s4 << 5) + j]);
        a5 += __half2float(hin[(s5 << 5) + j]);
        a6 += __half2float(hin[(s6 << 5) + j]);
        a7 += __half2float(hin[(s7 << 5) + j]);
    }
    for (; e < e1; ++e) a0 += __half2float(hin[(src_sorted[e] << 5) + j]);
    float acc = ((a0 + a1) + (a2 + a3)) + ((a4 + a5) + (a6 + a7));
    // x4_j = agg . W3[:,j] + b3[j]   (no relu on layer 4)
    float o = b3[j];
#pragma unroll
    for (int k = 0; k < 32; ++k) o = fmaf(__shfl(acc, k, 32), W3[k * 32 + j], o);
    // u_j = x4 . W5[0:32, j] + b5[j] ; v_j = x4 . W5[32:64, j]
    float u = b5[j], v = 0.f;
#pragma unroll
    for (int k = 0; k < 32; ++k) {
        float xk = __shfl(o, k, 32);
        u = fmaf(xk, W5[k * 32 + j], u);
        v = fmaf(xk, W5[(32 + k) * 32 + j], v);
    }
    u16[(g << 5) + j] = __float2half_rn(u);
    v16[(g << 5) + j] = __float2half_rn(v);
}

// ---- per-edge: h = prelu(u[s]+v[d]) ; pd = h.W6 + b6 ; persistence-image partials ----
__global__ __launch_bounds__(256) void k_edge(const int* __restrict__ src32, const int* __restrict__ dst32,
                                              const __half* __restrict__ u16, const __half* __restrict__ v16,
                                              const float* __restrict__ W6, const float* __restrict__ b6,
                                              float* __restrict__ pd_out, float* __restrict__ partial) {
    int e = blockIdx.x * 256 + threadIdx.x;  // EE divisible by 256, no tail
    int s = src32[e], d = dst32[e];

    const uint4* pu = reinterpret_cast<const uint4*>(u16 + ((size_t)s << 5));
    const uint4* pv = reinterpret_cast<const uint4*>(v16 + ((size_t)d << 5));

    float pd0 = b6[0], pd1 = b6[1];
#pragma unroll
    for (int q = 0; q < 4; ++q) {
        uint4 ua = pu[q];
        uint4 vb = pv[q];
        const __half2* ah = reinterpret_cast<const __half2*>(&ua);
        const __half2* bh = reinterpret_cast<const __half2*>(&vb);
#pragma unroll
        for (int r = 0; r < 4; ++r) {
            float2 f = __half22float2(__hadd2(ah[r], bh[r]));
            int j = q * 8 + 2 * r;
            float h0 = f.x >= 0.f ? f.x : 0.1f * f.x;
            float h1 = f.y >= 0.f ? f.y : 0.1f * f.y;
            pd0 = fmaf(h0, W6[2 * j + 0], pd0);
            pd1 = fmaf(h0, W6[2 * j + 1], pd1);
            pd0 = fmaf(h1, W6[2 * (j + 1) + 0], pd0);
            pd1 = fmaf(h1, W6[2 * (j + 1) + 1], pd1);
        }
    }
    pd_out[2 * (size_t)e + 0] = pd0;
    pd_out[2 * (size_t)e + 1] = pd1;

    // persistence image contribution
    float pers = pd1 - pd0;
    const float inv = 3.5355339059327378f;  // 1/(0.2*sqrt(2))
    float cb[6], cp[6];
#pragma unroll
    for (int i = 0; i < 6; ++i) {
        float te = 0.2f * (float)i;
        cb[i] = 0.5f * (1.f + erff((te - pd0) * inv));
        cp[i] = 0.5f * (1.f + erff((te - pers) * inv));
    }

    int lane = threadIdx.x & 63;
    int wv = threadIdx.x >> 6;
    __shared__ float sacc[4][25];
#pragma unroll
    for (int i = 0; i < 5; ++i) {
#pragma unroll
        for (int jj = 0; jj < 5; ++jj) {
            float v = pers * (cb[i + 1] - cb[i]) * (cp[jj + 1] - cp[jj]);
            v += __shfl_down(v, 32);
            v += __shfl_down(v, 16);
            v += __shfl_down(v, 8);
            v += __shfl_down(v, 4);
            v += __shfl_down(v, 2);
            v += __shfl_down(v, 1);
            if (lane == 0) sacc[wv][i * 5 + jj] = v;
        }
    }
    __syncthreads();
    if (threadIdx.x < 25) {
        partial[(size_t)blockIdx.x * 25 + threadIdx.x] =
            sacc[0][threadIdx.x] + sacc[1][threadIdx.x] + sacc[2][threadIdx.x] + sacc[3][threadIdx.x];
    }
}

// ---- deterministic final reduction of block partials per bin ----
__global__ __launch_bounds__(256) void k_img(const float* __restrict__ partial, float* __restrict__ img) {
    int bin = blockIdx.x;  // 25 blocks
    float s = 0.f;
    for (int k = threadIdx.x; k < EE / 256; k += 256) s += partial[(size_t)k * 25 + bin];
    s += __shfl_down(s, 32);
    s += __shfl_down(s, 16);
    s += __shfl_down(s, 8);
    s += __shfl_down(s, 4);
    s += __shfl_down(s, 2);
    s += __shfl_down(s, 1);
    __shared__ float wsum[4];
    if ((threadIdx.x & 63) == 0) wsum[threadIdx.x >> 6] = s;
    __syncthreads();
    if (threadIdx.x == 0) img[bin] = wsum[0] + wsum[1] + wsum[2] + wsum[3];
}

extern "C" void kernel_launch(void* const* d_in, const int* in_sizes, int n_in,
                              void* d_out, int out_size, void* d_ws, size_t ws_size,
                              hipStream_t stream) {
    const float* x0 = (const float*)d_in[0];
    // Harness converts integer inputs to int32: edge_index0 is (2, ET) int32.
    const int* src32 = (const int*)d_in[1];
    const int* dst32 = src32 + ET;
    const float* W1 = (const float*)d_in[2];
    const float* b1 = (const float*)d_in[3];
    const float* W2 = (const float*)d_in[4];
    const float* b2 = (const float*)d_in[5];
    const float* W4 = (const float*)d_in[6];
    const float* b4 = (const float*)d_in[7];
    const float* W3 = (const float*)d_in[8];
    const float* b3 = (const float*)d_in[9];
    const float* W5 = (const float*)d_in[10];
    const float* b5 = (const float*)d_in[11];
    const float* W6 = (const float*)d_in[12];
    const float* b6 = (const float*)d_in[13];
    float* out = (float*)d_out;

    char* w = (char*)d_ws;
    int2* pairs = (int2*)w;                          // ET int2
    int* bucket_cnt = (int*)(pairs + ET);            // NBKT
    int* bucket_base = bucket_cnt + NBKT;            // NBKT+1
    int* bucket_fill = bucket_base + NBKT + 1;       // NBKT
    int* rowptr = bucket_fill + NBKT;                // NN+1
    int* src_sorted = rowptr + NN + 1;               // ET
    // align to 16B for half tables
    size_t off = ((size_t)((char*)(src_sorted + ET) - w) + 63) & ~(size_t)63;
    __half* bufA = (__half*)(w + off);               // NN*32 halfs
    __half* bufB = bufA + (size_t)NN * 32;           // NN*32 halfs
    __half* u16 = bufB + (size_t)NN * 32;            // NN*32 halfs
    __half* v16 = u16 + (size_t)NN * 32;             // NN*32 halfs
    float* partial = (float*)(v16 + (size_t)NN * 32);// (EE/256)*25 floats

    // ---- build CSR via coarse-bucket counting sort ----
    k_zero<<<1, 128, 0, stream>>>(bucket_cnt, NBKT);
    k_bkt_count<<<NBLK_A, 256, 0, stream>>>(dst32, bucket_cnt);
    k_bkt_scan<<<1, 128, 0, stream>>>(bucket_cnt, bucket_base, bucket_fill);
    k_bkt_scatter<<<NBLK_A, 256, 0, stream>>>(src32, dst32, bucket_fill, pairs);
    k_bkt_csr<<<NBKT, 512, 0, stream>>>(pairs, bucket_base, rowptr, src_sorted);

    // ---- layer 1 (pull + 1->32 + relu) ----
    k_pull1<<<(NN * 32 + 255) / 256, 256, 0, stream>>>(rowptr, src_sorted, x0, W1, b1, bufA);
    // ---- layers 2-3: fused pull-agg + matmul (fp16 tables) ----
    k_agg_mm<1><<<(NN * 32 + 255) / 256, 256, 0, stream>>>(rowptr, src_sorted, bufA, W2, b2, bufB);
    k_agg_mm<1><<<(NN * 32 + 255) / 256, 256, 0, stream>>>(rowptr, src_sorted, bufB, W4, b4, bufA);
    // ---- layer 4 + per-node W5 projections (u,v in fp16) ----
    k_agg_mm_proj<<<(NN * 32 + 255) / 256, 256, 0, stream>>>(rowptr, src_sorted, bufA, W3, b3, W5, b5, u16, v16);

    // ---- edge MLP + persistence image ----
    k_edge<<<EE / 256, 256, 0, stream>>>(src32, dst32, u16, v16, W6, b6, out, partial);
    k_img<<<25, 256, 0, stream>>>(partial, out + 2 * (size_t)EE);
}

// Round 8
// 254.265 us; speedup vs baseline: 3.2092x; 1.2249x over previous
//
#include <hip/hip_runtime.h>
#include <hip/hip_bf16.h>
#include <hip/hip_fp16.h>
#include <math.h>

#define NN 100000
#define EE 1600000
#define ET 1700000   // E + N self-loops
#define HID 32

#define BKT_SHIFT 10
#define BKT_MASK 1023
#define NBKT 98            // ceil(NN / 1024)
#define EPB 4096           // edges per block in stage A
#define NBLK_A 416         // ceil(ET / EPB)

// ---- zero small int buffer ----
__global__ __launch_bounds__(128) void k_zero(int* __restrict__ p, int n) {
    int t = blockIdx.x * 128 + threadIdx.x;
    if (t < n) p[t] = 0;
}

// ---- stage A0: coarse bucket counts (LDS hist, one global atomic per block-bin) ----
__global__ __launch_bounds__(256) void k_bkt_count(const int* __restrict__ dst32, int* __restrict__ bucket_cnt) {
    __shared__ int h[NBKT];
    for (int i = threadIdx.x; i < NBKT; i += 256) h[i] = 0;
    __syncthreads();
    int base = blockIdx.x * EPB;
    for (int k = 0; k < EPB; k += 256) {
        int t = base + k + threadIdx.x;
        if (t < ET) atomicAdd(&h[dst32[t] >> BKT_SHIFT], 1);
    }
    __syncthreads();
    for (int i = threadIdx.x; i < NBKT; i += 256) {
        int c = h[i];
        if (c) atomicAdd(&bucket_cnt[i], c);
    }
}

// ---- stage A scan: exclusive scan of 98 bucket counts ----
__global__ __launch_bounds__(128) void k_bkt_scan(const int* __restrict__ bucket_cnt, int* __restrict__ bucket_base,
                                                  int* __restrict__ bucket_fill) {
    __shared__ int s[128];
    int t = threadIdx.x;
    int v = (t < NBKT) ? bucket_cnt[t] : 0;
    s[t] = v;
    for (int off = 1; off < 128; off <<= 1) {
        __syncthreads();
        int u = (t >= off) ? s[t - off] : 0;
        __syncthreads();
        s[t] += u;
    }
    __syncthreads();
    int ex = s[t] - v;
    if (t < NBKT) {
        bucket_base[t] = ex;
        bucket_fill[t] = ex;
    }
    if (t == 0) bucket_base[NBKT] = ET;
}

// ---- stage A1: scatter (src,dst) pairs into coarse bucket regions, long sequential runs ----
__global__ __launch_bounds__(256) void k_bkt_scatter(const int* __restrict__ src32, const int* __restrict__ dst32,
                                                     int* __restrict__ bucket_fill, int2* __restrict__ pairs) {
    __shared__ int h[NBKT];
    __shared__ int bbase[NBKT];
    for (int i = threadIdx.x; i < NBKT; i += 256) h[i] = 0;
    __syncthreads();
    int base = blockIdx.x * EPB;
    for (int k = 0; k < EPB; k += 256) {
        int t = base + k + threadIdx.x;
        if (t < ET) atomicAdd(&h[dst32[t] >> BKT_SHIFT], 1);
    }
    __syncthreads();
    for (int i = threadIdx.x; i < NBKT; i += 256) {
        int c = h[i];
        bbase[i] = c ? atomicAdd(&bucket_fill[i], c) : 0;
        h[i] = 0;  // becomes local fill counter (same thread owns bin -> no race)
    }
    __syncthreads();
    for (int k = 0; k < EPB; k += 256) {
        int t = base + k + threadIdx.x;
        if (t < ET) {
            int sv = src32[t], dv = dst32[t];
            int b = dv >> BKT_SHIFT;
            int off = atomicAdd(&h[b], 1);
            pairs[bbase[b] + off] = make_int2(sv, dv);
        }
    }
}

// ---- stage B: per-bucket fine CSR (1024 nodes in LDS) + in-bucket scatter of src ----
__global__ __launch_bounds__(512) void k_bkt_csr(const int2* __restrict__ pairs, const int* __restrict__ bucket_base,
                                                 int* __restrict__ rowptr, int* __restrict__ src_sorted) {
    __shared__ int h[1024];
    __shared__ int tmp[512];
    int t = threadIdx.x;
    int b = blockIdx.x;
    int e0 = bucket_base[b], e1 = bucket_base[b + 1];
    int node0 = b << BKT_SHIFT;

    h[t] = 0;
    h[t + 512] = 0;
    __syncthreads();
    for (int e = e0 + t; e < e1; e += 512) atomicAdd(&h[pairs[e].y & BKT_MASK], 1);
    __syncthreads();

    int i0 = 2 * t, i1 = 2 * t + 1;
    int v0 = h[i0], v1 = h[i1];
    int s = v0 + v1;
    tmp[t] = s;
    for (int off = 1; off < 512; off <<= 1) {
        __syncthreads();
        int u = (t >= off) ? tmp[t - off] : 0;
        __syncthreads();
        tmp[t] += u;
    }
    __syncthreads();
    int excl = tmp[t] - s;
    h[i0] = excl;
    h[i1] = excl + v0;
    __syncthreads();

    for (int i = t; i < 1024; i += 512) {
        int node = node0 + i;
        if (node < NN) rowptr[node] = e0 + h[i];
    }
    if (b == 0 && t == 0) rowptr[NN] = ET;
    __syncthreads();

    for (int e = e0 + t; e < e1; e += 512) {
        int2 p = pairs[e];
        int sl = atomicAdd(&h[p.y & BKT_MASK], 1);
        src_sorted[e0 + sl] = p.x;
    }
}

// ---- helpers ----
__device__ __forceinline__ void acc4(uint2 r, float& c0, float& c1, float& c2, float& c3) {
    __half2 h0 = *reinterpret_cast<__half2*>(&r.x);
    __half2 h1 = *reinterpret_cast<__half2*>(&r.y);
    float2 f0 = __half22float2(h0);
    float2 f1 = __half22float2(h1);
    c0 += f0.x; c1 += f0.y; c2 += f1.x; c3 += f1.y;
}

// ---- layer 1a: thread-per-node scalar pull-agg of x0 ----
__global__ __launch_bounds__(256) void k_pull1a(const int* __restrict__ rowptr, const int* __restrict__ src_sorted,
                                                const float* __restrict__ x0, float* __restrict__ agg0) {
    int g = blockIdx.x * 256 + threadIdx.x;
    if (g >= NN) return;
    int e0 = rowptr[g], e1 = rowptr[g + 1];
    float a0 = x0[g], a1 = 0.f, a2 = 0.f, a3 = 0.f, a4 = 0.f, a5 = 0.f, a6 = 0.f, a7 = 0.f;
    int e = e0;
    for (; e + 8 <= e1; e += 8) {
        a0 += x0[src_sorted[e + 0]];
        a1 += x0[src_sorted[e + 1]];
        a2 += x0[src_sorted[e + 2]];
        a3 += x0[src_sorted[e + 3]];
        a4 += x0[src_sorted[e + 4]];
        a5 += x0[src_sorted[e + 5]];
        a6 += x0[src_sorted[e + 6]];
        a7 += x0[src_sorted[e + 7]];
    }
    for (; e < e1; ++e) a0 += x0[src_sorted[e]];
    agg0[g] = ((a0 + a1) + (a2 + a3)) + ((a4 + a5) + (a6 + a7));
}

// ---- layer 1b: expand agg0 -> h1 = relu(agg0*W1 + b1), 8 lanes/node ----
__global__ __launch_bounds__(256) void k_pull1b(const float* __restrict__ agg0, const float* __restrict__ W1,
                                                const float* __restrict__ b1, __half* __restrict__ hout) {
    int t = blockIdx.x * 256 + threadIdx.x;   // NN*8 threads
    int g = t >> 3, j = t & 7;
    float s = agg0[g];
    float o0 = fmaxf(fmaf(s, W1[4 * j + 0], b1[4 * j + 0]), 0.f);
    float o1 = fmaxf(fmaf(s, W1[4 * j + 1], b1[4 * j + 1]), 0.f);
    float o2 = fmaxf(fmaf(s, W1[4 * j + 2], b1[4 * j + 2]), 0.f);
    float o3 = fmaxf(fmaf(s, W1[4 * j + 3], b1[4 * j + 3]), 0.f);
    __half2 p0 = __floats2half2_rn(o0, o1);
    __half2 p1 = __floats2half2_rn(o2, o3);
    uint2 st = make_uint2(*reinterpret_cast<unsigned*>(&p0), *reinterpret_cast<unsigned*>(&p1));
    reinterpret_cast<uint2*>(hout)[(g << 3) + j] = st;
}

// ---- fused pull-agg + 32x32 matmul (+relu), 8 lanes/node, uint2 gathers, 8-deep ILP ----
template <int RELU>
__global__ __launch_bounds__(256) void k_agg_mm(const int* __restrict__ rowptr, const int* __restrict__ src_sorted,
                                                const __half* __restrict__ hin, const float* __restrict__ W,
                                                const float* __restrict__ b, __half* __restrict__ hout) {
    __shared__ float Wl[1024];
    for (int i = threadIdx.x; i < 1024; i += 256) Wl[i] = W[i];
    __syncthreads();
    int g = (blockIdx.x * 256 + threadIdx.x) >> 3;   // NN*8 threads, exact grid
    int j = threadIdx.x & 7;
    const uint2* tab = reinterpret_cast<const uint2*>(hin);
    int e0 = rowptr[g], e1 = rowptr[g + 1];
    float x0, x1, x2, x3;
    {
        uint2 r = tab[(g << 3) + j];
        __half2 h0 = *reinterpret_cast<__half2*>(&r.x);
        __half2 h1 = *reinterpret_cast<__half2*>(&r.y);
        float2 f0 = __half22float2(h0), f1 = __half22float2(h1);
        x0 = f0.x; x1 = f0.y; x2 = f1.x; x3 = f1.y;
    }
    float y0 = 0.f, y1 = 0.f, y2 = 0.f, y3 = 0.f;
    int e = e0;
    for (; e + 8 <= e1; e += 8) {
        int s0 = src_sorted[e + 0], s1 = src_sorted[e + 1], s2 = src_sorted[e + 2], s3 = src_sorted[e + 3];
        int s4 = src_sorted[e + 4], s5 = src_sorted[e + 5], s6 = src_sorted[e + 6], s7 = src_sorted[e + 7];
        uint2 r0 = tab[(s0 << 3) + j];
        uint2 r1 = tab[(s1 << 3) + j];
        uint2 r2 = tab[(s2 << 3) + j];
        uint2 r3 = tab[(s3 << 3) + j];
        uint2 r4 = tab[(s4 << 3) + j];
        uint2 r5 = tab[(s5 << 3) + j];
        uint2 r6 = tab[(s6 << 3) + j];
        uint2 r7 = tab[(s7 << 3) + j];
        acc4(r0, x0, x1, x2, x3);
        acc4(r1, y0, y1, y2, y3);
        acc4(r2, x0, x1, x2, x3);
        acc4(r3, y0, y1, y2, y3);
        acc4(r4, x0, x1, x2, x3);
        acc4(r5, y0, y1, y2, y3);
        acc4(r6, x0, x1, x2, x3);
        acc4(r7, y0, y1, y2, y3);
    }
    for (; e < e1; ++e) {
        uint2 r = tab[(src_sorted[e] << 3) + j];
        acc4(r, x0, x1, x2, x3);
    }
    x0 += y0; x1 += y1; x2 += y2; x3 += y3;

    float o0 = b[4 * j + 0], o1 = b[4 * j + 1], o2 = b[4 * j + 2], o3 = b[4 * j + 3];
#pragma unroll
    for (int k = 0; k < 8; ++k) {
        float f0 = __shfl(x0, k, 8);
        float f1 = __shfl(x1, k, 8);
        float f2 = __shfl(x2, k, 8);
        float f3 = __shfl(x3, k, 8);
        float4 w0 = *reinterpret_cast<const float4*>(&Wl[(4 * k + 0) * 32 + 4 * j]);
        float4 w1 = *reinterpret_cast<const float4*>(&Wl[(4 * k + 1) * 32 + 4 * j]);
        float4 w2 = *reinterpret_cast<const float4*>(&Wl[(4 * k + 2) * 32 + 4 * j]);
        float4 w3 = *reinterpret_cast<const float4*>(&Wl[(4 * k + 3) * 32 + 4 * j]);
        o0 = fmaf(f0, w0.x, o0); o1 = fmaf(f0, w0.y, o1); o2 = fmaf(f0, w0.z, o2); o3 = fmaf(f0, w0.w, o3);
        o0 = fmaf(f1, w1.x, o0); o1 = fmaf(f1, w1.y, o1); o2 = fmaf(f1, w1.z, o2); o3 = fmaf(f1, w1.w, o3);
        o0 = fmaf(f2, w2.x, o0); o1 = fmaf(f2, w2.y, o1); o2 = fmaf(f2, w2.z, o2); o3 = fmaf(f2, w2.w, o3);
        o0 = fmaf(f3, w3.x, o0); o1 = fmaf(f3, w3.y, o1); o2 = fmaf(f3, w3.z, o2); o3 = fmaf(f3, w3.w, o3);
    }
    if (RELU) {
        o0 = fmaxf(o0, 0.f); o1 = fmaxf(o1, 0.f); o2 = fmaxf(o2, 0.f); o3 = fmaxf(o3, 0.f);
    }
    __half2 p0 = __floats2half2_rn(o0, o1);
    __half2 p1 = __floats2half2_rn(o2, o3);
    uint2 st = make_uint2(*reinterpret_cast<unsigned*>(&p0), *reinterpret_cast<unsigned*>(&p1));
    reinterpret_cast<uint2*>(hout)[(g << 3) + j] = st;
}

// ---- layer 4 fused: pull-agg + W3 matmul + W5 projections -> u16 (b5 folded), v16 ----
__global__ __launch_bounds__(256) void k_agg_mm_proj(const int* __restrict__ rowptr, const int* __restrict__ src_sorted,
                                                     const __half* __restrict__ hin, const float* __restrict__ W3,
                                                     const float* __restrict__ b3,
                                                     const float* __restrict__ W5, const float* __restrict__ b5,
                                                     __half* __restrict__ u16, __half* __restrict__ v16) {
    __shared__ float W3l[1024];
    __shared__ float W5l[2048];
    for (int i = threadIdx.x; i < 1024; i += 256) W3l[i] = W3[i];
    for (int i = threadIdx.x; i < 2048; i += 256) W5l[i] = W5[i];
    __syncthreads();
    int g = (blockIdx.x * 256 + threadIdx.x) >> 3;
    int j = threadIdx.x & 7;
    const uint2* tab = reinterpret_cast<const uint2*>(hin);
    int e0 = rowptr[g], e1 = rowptr[g + 1];
    float x0, x1, x2, x3;
    {
        uint2 r = tab[(g << 3) + j];
        __half2 h0 = *reinterpret_cast<__half2*>(&r.x);
        __half2 h1 = *reinterpret_cast<__half2*>(&r.y);
        float2 f0 = __half22float2(h0), f1 = __half22float2(h1);
        x0 = f0.x; x1 = f0.y; x2 = f1.x; x3 = f1.y;
    }
    float y0 = 0.f, y1 = 0.f, y2 = 0.f, y3 = 0.f;
    int e = e0;
    for (; e + 8 <= e1; e += 8) {
        int s0 = src_sorted[e + 0], s1 = src_sorted[e + 1], s2 = src_sorted[e + 2], s3 = src_sorted[e + 3];
        int s4 = src_sorted[e + 4], s5 = src_sorted[e + 5], s6 = src_sorted[e + 6], s7 = src_sorted[e + 7];
        uint2 r0 = tab[(s0 << 3) + j];
        uint2 r1 = tab[(s1 << 3) + j];
        uint2 r2 = tab[(s2 << 3) + j];
        uint2 r3 = tab[(s3 << 3) + j];
        uint2 r4 = tab[(s4 << 3) + j];
        uint2 r5 = tab[(s5 << 3) + j];
        uint2 r6 = tab[(s6 << 3) + j];
        uint2 r7 = tab[(s7 << 3) + j];
        acc4(r0, x0, x1, x2, x3);
        acc4(r1, y0, y1, y2, y3);
        acc4(r2, x0, x1, x2, x3);
        acc4(r3, y0, y1, y2, y3);
        acc4(r4, x0, x1, x2, x3);
        acc4(r5, y0, y1, y2, y3);
        acc4(r6, x0, x1, x2, x3);
        acc4(r7, y0, y1, y2, y3);
    }
    for (; e < e1; ++e) {
        uint2 r = tab[(src_sorted[e] << 3) + j];
        acc4(r, x0, x1, x2, x3);
    }
    x0 += y0; x1 += y1; x2 += y2; x3 += y3;

    // x4 = agg . W3 + b3 (no relu)
    float o0 = b3[4 * j + 0], o1 = b3[4 * j + 1], o2 = b3[4 * j + 2], o3 = b3[4 * j + 3];
#pragma unroll
    for (int k = 0; k < 8; ++k) {
        float f0 = __shfl(x0, k, 8);
        float f1 = __shfl(x1, k, 8);
        float f2 = __shfl(x2, k, 8);
        float f3 = __shfl(x3, k, 8);
        float4 w0 = *reinterpret_cast<const float4*>(&W3l[(4 * k + 0) * 32 + 4 * j]);
        float4 w1 = *reinterpret_cast<const float4*>(&W3l[(4 * k + 1) * 32 + 4 * j]);
        float4 w2 = *reinterpret_cast<const float4*>(&W3l[(4 * k + 2) * 32 + 4 * j]);
        float4 w3 = *reinterpret_cast<const float4*>(&W3l[(4 * k + 3) * 32 + 4 * j]);
        o0 = fmaf(f0, w0.x, o0); o1 = fmaf(f0, w0.y, o1); o2 = fmaf(f0, w0.z, o2); o3 = fmaf(f0, w0.w, o3);
        o0 = fmaf(f1, w1.x, o0); o1 = fmaf(f1, w1.y, o1); o2 = fmaf(f1, w1.z, o2); o3 = fmaf(f1, w1.w, o3);
        o0 = fmaf(f2, w2.x, o0); o1 = fmaf(f2, w2.y, o1); o2 = fmaf(f2, w2.z, o2); o3 = fmaf(f2, w2.w, o3);
        o0 = fmaf(f3, w3.x, o0); o1 = fmaf(f3, w3.y, o1); o2 = fmaf(f3, w3.z, o2); o3 = fmaf(f3, w3.w, o3);
    }
    // u = x4 . W5[0:32,:] + b5 ; v = x4 . W5[32:64,:]
    float u0 = b5[4 * j + 0], u1 = b5[4 * j + 1], u2 = b5[4 * j + 2], u3 = b5[4 * j + 3];
    float v0 = 0.f, v1 = 0.f, v2 = 0.f, v3 = 0.f;
#pragma unroll
    for (int k = 0; k < 8; ++k) {
        float f0 = __shfl(o0, k, 8);
        float f1 = __shfl(o1, k, 8);
        float f2 = __shfl(o2, k, 8);
        float f3 = __shfl(o3, k, 8);
        float4 a0 = *reinterpret_cast<const float4*>(&W5l[(4 * k + 0) * 32 + 4 * j]);
        float4 a1 = *reinterpret_cast<const float4*>(&W5l[(4 * k + 1) * 32 + 4 * j]);
        float4 a2 = *reinterpret_cast<const float4*>(&W5l[(4 * k + 2) * 32 + 4 * j]);
        float4 a3 = *reinterpret_cast<const float4*>(&W5l[(4 * k + 3) * 32 + 4 * j]);
        u0 = fmaf(f0, a0.x, u0); u1 = fmaf(f0, a0.y, u1); u2 = fmaf(f0, a0.z, u2); u3 = fmaf(f0, a0.w, u3);
        u0 = fmaf(f1, a1.x, u0); u1 = fmaf(f1, a1.y, u1); u2 = fmaf(f1, a1.z, u2); u3 = fmaf(f1, a1.w, u3);
        u0 = fmaf(f2, a2.x, u0); u1 = fmaf(f2, a2.y, u1); u2 = fmaf(f2, a2.z, u2); u3 = fmaf(f2, a2.w, u3);
        u0 = fmaf(f3, a3.x, u0); u1 = fmaf(f3, a3.y, u1); u2 = fmaf(f3, a3.z, u2); u3 = fmaf(f3, a3.w, u3);
        float4 c0 = *reinterpret_cast<const float4*>(&W5l[(32 + 4 * k + 0) * 32 + 4 * j]);
        float4 c1 = *reinterpret_cast<const float4*>(&W5l[(32 + 4 * k + 1) * 32 + 4 * j]);
        float4 c2 = *reinterpret_cast<const float4*>(&W5l[(32 + 4 * k + 2) * 32 + 4 * j]);
        float4 c3 = *reinterpret_cast<const float4*>(&W5l[(32 + 4 * k + 3) * 32 + 4 * j]);
        v0 = fmaf(f0, c0.x, v0); v1 = fmaf(f0, c0.y, v1); v2 = fmaf(f0, c0.z, v2); v3 = fmaf(f0, c0.w, v3);
        v0 = fmaf(f1, c1.x, v0); v1 = fmaf(f1, c1.y, v1); v2 = fmaf(f1, c1.z, v2); v3 = fmaf(f1, c1.w, v3);
        v0 = fmaf(f2, c2.x, v0); v1 = fmaf(f2, c2.y, v1); v2 = fmaf(f2, c2.z, v2); v3 = fmaf(f2, c2.w, v3);
        v0 = fmaf(f3, c3.x, v0); v1 = fmaf(f3, c3.y, v1); v2 = fmaf(f3, c3.z, v2); v3 = fmaf(f3, c3.w, v3);
    }
    __half2 pu0 = __floats2half2_rn(u0, u1);
    __half2 pu1 = __floats2half2_rn(u2, u3);
    uint2 su = make_uint2(*reinterpret_cast<unsigned*>(&pu0), *reinterpret_cast<unsigned*>(&pu1));
    reinterpret_cast<uint2*>(u16)[(g << 3) + j] = su;
    __half2 pv0 = __floats2half2_rn(v0, v1);
    __half2 pv1 = __floats2half2_rn(v2, v3);
    uint2 sv = make_uint2(*reinterpret_cast<unsigned*>(&pv0), *reinterpret_cast<unsigned*>(&pv1));
    reinterpret_cast<uint2*>(v16)[(g << 3) + j] = sv;
}

// ---- per-edge (2 edges/thread): h = prelu(u[s]+v[d]); pd = h.W6 + b6; img partials ----
__device__ __forceinline__ void edge_pd(const uint4* pu, const uint4* pv, const float* W6,
                                        float b60, float b61, float& pd0, float& pd1) {
    pd0 = b60; pd1 = b61;
#pragma unroll
    for (int q = 0; q < 4; ++q) {
        uint4 ua = pu[q];
        uint4 vb = pv[q];
        const __half2* ah = reinterpret_cast<const __half2*>(&ua);
        const __half2* bh = reinterpret_cast<const __half2*>(&vb);
#pragma unroll
        for (int r = 0; r < 4; ++r) {
            float2 f = __half22float2(__hadd2(ah[r], bh[r]));
            int jj = q * 8 + 2 * r;
            float h0 = f.x >= 0.f ? f.x : 0.1f * f.x;
            float h1 = f.y >= 0.f ? f.y : 0.1f * f.y;
            pd0 = fmaf(h0, W6[2 * jj + 0], pd0);
            pd1 = fmaf(h0, W6[2 * jj + 1], pd1);
            pd0 = fmaf(h1, W6[2 * (jj + 1) + 0], pd0);
            pd1 = fmaf(h1, W6[2 * (jj + 1) + 1], pd1);
        }
    }
}

__global__ __launch_bounds__(256) void k_edge(const int* __restrict__ src32, const int* __restrict__ dst32,
                                              const __half* __restrict__ u16, const __half* __restrict__ v16,
                                              const float* __restrict__ W6, const float* __restrict__ b6,
                                              float* __restrict__ pd_out, float* __restrict__ partial) {
    int ea = blockIdx.x * 512 + threadIdx.x;   // EE divisible by 512
    int eb = ea + 256;
    int sa = src32[ea], da = dst32[ea];
    int sb = src32[eb], db = dst32[eb];
    const uint4* pua = reinterpret_cast<const uint4*>(u16 + ((size_t)sa << 5));
    const uint4* pva = reinterpret_cast<const uint4*>(v16 + ((size_t)da << 5));
    const uint4* pub = reinterpret_cast<const uint4*>(u16 + ((size_t)sb << 5));
    const uint4* pvb = reinterpret_cast<const uint4*>(v16 + ((size_t)db << 5));
    float b60 = b6[0], b61 = b6[1];

    float pda0, pda1, pdb0, pdb1;
    edge_pd(pua, pva, W6, b60, b61, pda0, pda1);
    edge_pd(pub, pvb, W6, b60, b61, pdb0, pdb1);
    reinterpret_cast<float2*>(pd_out)[ea] = make_float2(pda0, pda1);
    reinterpret_cast<float2*>(pd_out)[eb] = make_float2(pdb0, pdb1);

    float persA = pda1 - pda0;
    float persB = pdb1 - pdb0;
    const float inv = 3.5355339059327378f;  // 1/(0.2*sqrt(2))
    float cbA[6], cpA[6], cbB[6], cpB[6];
#pragma unroll
    for (int i = 0; i < 6; ++i) {
        float te = 0.2f * (float)i;
        cbA[i] = 0.5f * (1.f + erff((te - pda0) * inv));
        cpA[i] = 0.5f * (1.f + erff((te - persA) * inv));
        cbB[i] = 0.5f * (1.f + erff((te - pdb0) * inv));
        cpB[i] = 0.5f * (1.f + erff((te - persB) * inv));
    }

    int lane = threadIdx.x & 63;
    int wv = threadIdx.x >> 6;
    __shared__ float sacc[4][25];
#pragma unroll
    for (int i = 0; i < 5; ++i) {
#pragma unroll
        for (int jj = 0; jj < 5; ++jj) {
            float v = persA * (cbA[i + 1] - cbA[i]) * (cpA[jj + 1] - cpA[jj])
                    + persB * (cbB[i + 1] - cbB[i]) * (cpB[jj + 1] - cpB[jj]);
            v += __shfl_down(v, 32);
            v += __shfl_down(v, 16);
            v += __shfl_down(v, 8);
            v += __shfl_down(v, 4);
            v += __shfl_down(v, 2);
            v += __shfl_down(v, 1);
            if (lane == 0) sacc[wv][i * 5 + jj] = v;
        }
    }
    __syncthreads();
    if (threadIdx.x < 25) {
        partial[(size_t)blockIdx.x * 25 + threadIdx.x] =
            sacc[0][threadIdx.x] + sacc[1][threadIdx.x] + sacc[2][threadIdx.x] + sacc[3][threadIdx.x];
    }
}

// ---- deterministic final reduction of block partials per bin ----
__global__ __launch_bounds__(256) void k_img(const float* __restrict__ partial, float* __restrict__ img) {
    int bin = blockIdx.x;  // 25 blocks
    float s = 0.f;
    for (int k = threadIdx.x; k < EE / 512; k += 256) s += partial[(size_t)k * 25 + bin];
    s += __shfl_down(s, 32);
    s += __shfl_down(s, 16);
    s += __shfl_down(s, 8);
    s += __shfl_down(s, 4);
    s += __shfl_down(s, 2);
    s += __shfl_down(s, 1);
    __shared__ float wsum[4];
    if ((threadIdx.x & 63) == 0) wsum[threadIdx.x >> 6] = s;
    __syncthreads();
    if (threadIdx.x == 0) img[bin] = wsum[0] + wsum[1] + wsum[2] + wsum[3];
}

extern "C" void kernel_launch(void* const* d_in, const int* in_sizes, int n_in,
                              void* d_out, int out_size, void* d_ws, size_t ws_size,
                              hipStream_t stream) {
    const float* x0 = (const float*)d_in[0];
    // Harness converts integer inputs to int32: edge_index0 is (2, ET) int32.
    const int* src32 = (const int*)d_in[1];
    const int* dst32 = src32 + ET;
    const float* W1 = (const float*)d_in[2];
    const float* b1 = (const float*)d_in[3];
    const float* W2 = (const float*)d_in[4];
    const float* b2 = (const float*)d_in[5];
    const float* W4 = (const float*)d_in[6];
    const float* b4 = (const float*)d_in[7];
    const float* W3 = (const float*)d_in[8];
    const float* b3 = (const float*)d_in[9];
    const float* W5 = (const float*)d_in[10];
    const float* b5 = (const float*)d_in[11];
    const float* W6 = (const float*)d_in[12];
    const float* b6 = (const float*)d_in[13];
    float* out = (float*)d_out;

    char* w = (char*)d_ws;
    int2* pairs = (int2*)w;                          // ET int2
    int* bucket_cnt = (int*)(pairs + ET);            // NBKT
    int* bucket_base = bucket_cnt + NBKT;            // NBKT+1
    int* bucket_fill = bucket_base + NBKT + 1;       // NBKT
    int* rowptr = bucket_fill + NBKT;                // NN+1
    int* src_sorted = rowptr + NN + 1;               // ET
    size_t off = ((size_t)((char*)(src_sorted + ET) - w) + 63) & ~(size_t)63;
    __half* bufA = (__half*)(w + off);               // NN*32 halfs
    __half* bufB = bufA + (size_t)NN * 32;           // NN*32 halfs
    __half* u16 = bufB + (size_t)NN * 32;            // NN*32 halfs
    __half* v16 = u16 + (size_t)NN * 32;             // NN*32 halfs
    float* agg0 = (float*)(v16 + (size_t)NN * 32);   // NN floats
    float* partial = agg0 + NN;                      // (EE/512)*25 floats

    // ---- build CSR via coarse-bucket counting sort ----
    k_zero<<<1, 128, 0, stream>>>(bucket_cnt, NBKT);
    k_bkt_count<<<NBLK_A, 256, 0, stream>>>(dst32, bucket_cnt);
    k_bkt_scan<<<1, 128, 0, stream>>>(bucket_cnt, bucket_base, bucket_fill);
    k_bkt_scatter<<<NBLK_A, 256, 0, stream>>>(src32, dst32, bucket_fill, pairs);
    k_bkt_csr<<<NBKT, 512, 0, stream>>>(pairs, bucket_base, rowptr, src_sorted);

    // ---- layer 1 ----
    k_pull1a<<<(NN + 255) / 256, 256, 0, stream>>>(rowptr, src_sorted, x0, agg0);
    k_pull1b<<<NN * 8 / 256, 256, 0, stream>>>(agg0, W1, b1, bufA);
    // ---- layers 2-3 ----
    k_agg_mm<1><<<NN * 8 / 256, 256, 0, stream>>>(rowptr, src_sorted, bufA, W2, b2, bufB);
    k_agg_mm<1><<<NN * 8 / 256, 256, 0, stream>>>(rowptr, src_sorted, bufB, W4, b4, bufA);
    // ---- layer 4 + W5 projections ----
    k_agg_mm_proj<<<NN * 8 / 256, 256, 0, stream>>>(rowptr, src_sorted, bufA, W3, b3, W5, b5, u16, v16);

    // ---- edge MLP + persistence image ----
    k_edge<<<EE / 512, 256, 0, stream>>>(src32, dst32, u16, v16, W6, b6, out, partial);
    k_img<<<25, 256, 0, stream>>>(partial, out + 2 * (size_t)EE);
}